// Round 1
// baseline (213.069 us; speedup 1.0000x reference)
//
#include <hip/hip_runtime.h>
#include <hip/hip_bf16.h>

#define D_MODEL 1024
#define NUM_HEADS 16
#define HEAD_DIM 64
#define SEQ 2048
#define BATCH 2
#define ROWS (BATCH * SEQ)  // 4096

typedef unsigned short u16;
typedef __bf16 bf16x8 __attribute__((ext_vector_type(8)));
typedef float f32x4 __attribute__((ext_vector_type(4)));

__device__ inline u16 f2bfu(float f) {
  // RNE float->bf16
  unsigned u = __float_as_uint(f);
  unsigned r = (u + 0x7fffu + ((u >> 16) & 1u)) >> 16;
  return (u16)r;
}

// packed f32x2 -> bf16x2 (one v_cvt_pk_bf16_f32 on gfx950; RNE fallback otherwise)
__device__ inline unsigned cvt_pk_bf16(float a, float b) {
#if __has_builtin(__builtin_amdgcn_cvt_pk_bf16_f32)
  auto r = __builtin_amdgcn_cvt_pk_bf16_f32(a, b);
  unsigned u;
  __builtin_memcpy(&u, &r, 4);
  return u;
#else
  return (unsigned)f2bfu(a) | ((unsigned)f2bfu(b) << 16);
#endif
}

__device__ inline f32x4 mfma16(bf16x8 a, bf16x8 b, f32x4 c) {
  return __builtin_amdgcn_mfma_f32_16x16x32_bf16(a, b, c, 0, 0, 0);
}

__device__ inline bf16x8 load_frag(const u16* p) {
  union { uint4 v; bf16x8 f; } u;
  u.v = *(const uint4*)p;
  return u.f;
}

// async global->LDS, 16B per lane; LDS dest = wave-uniform base + lane*16
__device__ inline void gload_lds16(const u16* g, u16* l) {
  __builtin_amdgcn_global_load_lds((const __attribute__((address_space(1))) void*)g,
                                   (__attribute__((address_space(3))) void*)l, 16, 0, 0);
}

// ---------------- fused prep: cvt x + transpose-cvt both weight matrices ----------------
// grid: [0,4096) cvt_x chunks; [4096,7168) W_qkv 32x32 tiles; [7168,8192) W_out tiles.

__global__ __launch_bounds__(256) void prep_kernel(const float* __restrict__ x,
                                                   u16* __restrict__ xb,
                                                   const float* __restrict__ Wq,
                                                   u16* __restrict__ WqT,
                                                   const float* __restrict__ Wo,
                                                   u16* __restrict__ WoT) {
  __shared__ float t[32][33];
  const int bid = blockIdx.x;
  if (bid < 4096) {
    int i = bid * 256 + threadIdx.x;  // 4 floats each
    float4 v = ((const float4*)x)[i];
    uint2 o;
    o.x = cvt_pk_bf16(v.x, v.y);
    o.y = cvt_pk_bf16(v.z, v.w);
    ((uint2*)xb)[i] = o;
    return;
  }
  const float* W;
  u16* Wt;
  int N, tIdx;
  if (bid < 4096 + 3072) { W = Wq; Wt = WqT; N = 3072; tIdx = bid - 4096; }
  else                   { W = Wo; Wt = WoT; N = 1024; tIdx = bid - 7168; }
  const int k0 = (tIdx & 31) * 32, n0 = (tIdx >> 5) * 32;
  const int c = threadIdx.x & 31, r8 = threadIdx.x >> 5;
#pragma unroll
  for (int i = 0; i < 4; i++) {
    int r = r8 + i * 8;
    t[r][c] = W[(size_t)(k0 + r) * N + n0 + c];
  }
  __syncthreads();
#pragma unroll
  for (int i = 0; i < 4; i++) {
    int r = r8 + i * 8;
    Wt[(size_t)(n0 + r) * 1024 + k0 + c] = f2bfu(t[c][r]);
  }
}

// ---------------- GEMM 1: qkv = x @ W_qkv + b -> Qb/Kb [bh][s][64], Vt [bh][d][s] ----------------
// 256x256 tile, BK=64, 8 waves (2M x 4N), 8-phase schedule with counted vmcnt (T3+T4)
// + setprio around MFMA cluster (T5). LDS = 8 half-tile slots x 16 KiB = 128 KiB,
// fragment-order layout (stage and ds_read both wave-linear -> zero bank conflicts,
// no swizzle needed). vmcnt(4) only at K-tile boundaries, never 0 in the main loop.
// Half-tile h (4 per K-tile: A.kh0, B.kh0, A.kh1, B.kh1) -> slot h%8; schedule keeps
// every staged slot >=1 phase + 1 barrier after its last reader.

__global__ __launch_bounds__(512, 2) void gemm_qkv(const u16* __restrict__ A,   // xb [4096][1024]
                                                   const u16* __restrict__ Bt,  // WqkvT [3072][1024]
                                                   const float* __restrict__ bias,
                                                   u16* __restrict__ Qb, u16* __restrict__ Kb,
                                                   u16* __restrict__ Vt) {
  __shared__ u16 lds[8 * 8192];  // 128 KiB
  const int tid = threadIdx.x;
  const int wave = tid >> 6, lane = tid & 63, ln = lane & 15, quad = lane >> 4;
  // bijective XCD swizzle: 192 blocks, 192%8==0; each XCD gets 24 contiguous tiles
  // = 2 full M-panel rows -> A panels L2-resident per XCD.
  const int lin = blockIdx.y * 12 + blockIdx.x;
  const int swz = (lin & 7) * 24 + (lin >> 3);
  const int n0 = (swz % 12) * 256, m0 = (swz / 12) * 256;
  const int wm = wave >> 2, wn = wave & 3;  // wave grid 2(M) x 4(N); per-wave 128x64 out
  f32x4 acc[8][4] = {};
  bf16x8 bfr[4];

  // per-thread staging bases (row = m0/n0 + chunk*16 + ln, k = koff + quad*8)
  const u16* aBase = A + (size_t)(m0 + ln) * 1024 + quad * 8;
  const u16* bBase = Bt + (size_t)(n0 + ln) * 1024 + quad * 8;
  u16* ldsW = lds + wave * 1024;  // wave stages frags 2w, 2w+1 of each half-tile

  auto stage = [&](int slot, int isB, int koff) __attribute__((always_inline)) {
    const u16* src = (isB ? bBase : aBase) + koff;
    u16* dst = ldsW + slot * 8192;
    gload_lds16(src + (size_t)(wave * 2) * 16384, dst);
    gload_lds16(src + (size_t)(wave * 2) * 16384 + 16384, dst + 512);
  };

  // one phase: 4 (or 8) ds_read_b128 || stage one half-tile -> (vmcnt) -> barrier ->
  // setprio(1) 16 MFMA setprio(0) -> barrier.   ph2: 0=kh0/Mlo 1=kh0/Mhi 2=kh1/Mlo 3=kh1/Mhi
  auto do_phase = [&](int bufbase, int ph2, int stSlot, int stIsB, int stKoff,
                      int wait) __attribute__((always_inline)) {
    const u16* aslot = lds + (bufbase + ((ph2 & 2) ? 2 : 0)) * 8192;
    const u16* bslot = lds + (bufbase + ((ph2 & 2) ? 3 : 1)) * 8192;
    const int mh = ph2 & 1;
    bf16x8 afr[4];
#pragma unroll
    for (int q = 0; q < 4; ++q)
      afr[q] = load_frag(aslot + (wm * 8 + mh * 4 + q) * 512 + quad * 128 + ln * 8);
    if (mh == 0) {
#pragma unroll
      for (int n = 0; n < 4; ++n)
        bfr[n] = load_frag(bslot + (wn * 4 + n) * 512 + quad * 128 + ln * 8);
    }
    if (stSlot >= 0) stage(stSlot, stIsB, stKoff);
    if (wait == 4) asm volatile("s_waitcnt vmcnt(4)" ::: "memory");
    if (wait == 0) asm volatile("s_waitcnt vmcnt(0)" ::: "memory");
    asm volatile("s_barrier" ::: "memory");
    __builtin_amdgcn_s_setprio(1);
#pragma unroll
    for (int q = 0; q < 4; ++q)
#pragma unroll
      for (int n = 0; n < 4; ++n)
        acc[mh * 4 + q][n] = mfma16(afr[q], bfr[n], acc[mh * 4 + q][n]);
    __builtin_amdgcn_s_setprio(0);
    asm volatile("s_barrier" ::: "memory");
  };

  // prologue: 6 half-tiles (K-tile 0 full + K-tile 1 kh0); vmcnt(4) -> K-tile 0 landed
  stage(0, 0, 0);  stage(1, 1, 0);
  stage(2, 0, 32); stage(3, 1, 32);
  stage(4, 0, 64); stage(5, 1, 64);
  asm volatile("s_waitcnt vmcnt(4)" ::: "memory");
  asm volatile("s_barrier" ::: "memory");

  // main loop: iteration i computes K-tiles 2i (buf0) / 2i+1 (buf1), stages h=8i+6..8i+13
#pragma unroll 1
  for (int i = 0; i < 7; ++i) {
    const int kA = 128 * i;
    do_phase(0, 0, 6, 0, kA + 96, -1);
    do_phase(0, 1, 7, 1, kA + 96, -1);
    do_phase(0, 2, 0, 0, kA + 128, -1);
    do_phase(0, 3, 1, 1, kA + 128, 4);   // certify K-tile 2i+1 before buf1 phases
    do_phase(4, 0, 2, 0, kA + 160, -1);
    do_phase(4, 1, 3, 1, kA + 160, -1);
    do_phase(4, 2, 4, 0, kA + 192, -1);
    do_phase(4, 3, 5, 1, kA + 192, 4);   // certify K-tile 2i+2
  }
  // epilogue: K-tiles 14 (buf0) and 15 (buf1); stage last 2 half-tiles, then drain
  do_phase(0, 0, 6, 0, 992, -1);
  do_phase(0, 1, 7, 1, 992, -1);
  do_phase(0, 2, -1, 0, 0, -1);
  do_phase(0, 3, -1, 0, 0, 0);           // vmcnt(0): K-tile 15 fully landed
  do_phase(4, 0, -1, 0, 0, -1);
  do_phase(4, 1, -1, 0, 0, -1);
  do_phase(4, 2, -1, 0, 0, -1);
  do_phase(4, 3, -1, 0, 0, -1);

  // C-write: identical scatter semantics to the validated 128^2 kernel
#pragma unroll
  for (int mf = 0; mf < 8; ++mf) {
    int row = m0 + wm * 128 + mf * 16 + quad * 4;
    int bb = row >> 11, s0 = row & 2047;
#pragma unroll
    for (int nf = 0; nf < 4; ++nf) {
      int col = n0 + wn * 64 + nf * 16 + ln;
      float bv = bias[col];
      int h = col / 192, rem = col - h * 192, t3 = rem >> 6, d = rem & 63;
      int bh = bb * NUM_HEADS + h;
      if (t3 == 2) {  // V -> transposed layout [bh][d][s], 4 consecutive s packed
        uint2 pk;
        pk.x = cvt_pk_bf16(acc[mf][nf][0] + bv, acc[mf][nf][1] + bv);
        pk.y = cvt_pk_bf16(acc[mf][nf][2] + bv, acc[mf][nf][3] + bv);
        *(uint2*)(Vt + ((size_t)bh * 64 + d) * SEQ + s0) = pk;
      } else {
        u16* dst = (t3 == 0) ? Qb : Kb;
#pragma unroll
        for (int r = 0; r < 4; ++r)
          dst[((size_t)bh * SEQ + s0 + r) * 64 + d] = f2bfu(acc[mf][nf][r] + bv);
      }
    }
  }
}

// ---------------- flash attention, balanced-pair blocks + 128-key super-tiles ----------------
// Block j (0..15): q-tiles lo=j, hi=31-j. 8 waves: 0-3 own lo rows, 4-7 own hi rows.
// Per super-iter: stage TWO 64-key tiles (K 16KB + Vt 16KB, single-buffered,
// global_load_lds w16, 4 chunks/wave), then ONE merged online-softmax update over
// 128 keys (halves softmax passes, barriers, alpha-rescales vs 64-key tiles).
// Phantom tail half is staged in-bounds (kt<=31) and masked to -1e30.

__global__ __launch_bounds__(512) void attn_kernel(const u16* __restrict__ Qb,
                                                   const u16* __restrict__ Kb,
                                                   const u16* __restrict__ Vt,
                                                   u16* __restrict__ Ob) {
  __shared__ u16 lK[2 * 64 * 64];  // two 64-key halves, fragment order (8 KB each)
  __shared__ u16 lV[2 * 64 * 64];
  __shared__ u16 lP[8][1152];      // per-wave P swizzle (1024 used) + epilogue (16x72)
  const int tid = threadIdx.x;
  const int wave = tid >> 6, lane = tid & 63;
  const int ln = lane & 15, quad = lane >> 4;
  const int j = blockIdx.x;  // 0..15 (j=0 heaviest, dispatched first)
  const int lo = j, hi = 31 - j;
  const int myt = (wave < 4) ? lo : hi;
  const int q0w = myt * 64 + (wave & 3) * 16;  // this wave's 16-row base
  const int sD = myt >> 1;                     // this wave's diagonal super-tile
  const int nsup = (hi + 2) >> 1;              // block-wide super-iteration count
  const int bh = blockIdx.y;
  const u16* Qg = Qb + (size_t)bh * SEQ * 64;
  const u16* Kg = Kb + (size_t)bh * SEQ * 64;
  const u16* Vg = Vt + (size_t)bh * 64 * SEQ;
  u16* lPw = lP[wave];

  // Q B-frags, loaded once
  bf16x8 qf[2];
#pragma unroll
  for (int ks = 0; ks < 2; ++ks)
    qf[ks] = load_frag(Qg + (size_t)(q0w + ln) * 64 + ks * 32 + quad * 8);

  // staging: 32 chunks of 1KB (16 K + 16 V), wave w owns c = w*4..w*4+3
  // (waves 0-3 all-K, waves 4-7 all-V -> uniform stride per wave)
  const u16* sp[4];
  u16* dp[4];
  const int sstep = (wave < 4) ? 128 * 64 : 128;  // K: +128 rows; V: +128 cols
#pragma unroll
  for (int i = 0; i < 4; ++i) {
    int c = wave * 4 + i;
    if (c < 16) {
      int half = c >> 3, cc = c & 7, rb = cc >> 1, kgh = cc & 1;
      sp[i] = Kg + (size_t)(half * 64 + rb * 16 + ln) * 64 + (kgh * 4 + quad) * 8;
      dp[i] = lK + half * 4096 + rb * 1024 + kgh * 512;
    } else {
      int c2 = c - 16, half = c2 >> 3, cc = c2 & 7, rb = cc >> 1, kgh = cc & 1;
      sp[i] = Vg + (size_t)(rb * 16 + ln) * SEQ + half * 64 + (kgh * 4 + quad) * 8;
      dp[i] = lV + half * 4096 + rb * 1024 + kgh * 512;
    }
  }

  f32x4 o[4] = {};     // O^T: row d=dt*16+quad*4+r, col q=ln
  float m_r = -1e30f;  // raw-score domain
  float l_r = 0.f;
  const float SC = 0.18033688011112042f;  // log2(e) / sqrt(64)
  const int qq = q0w + ln;

  for (int s = 0; s < nsup; ++s) {
    __syncthreads();  // previous super-tile fully consumed
#pragma unroll
    for (int i = 0; i < 4; ++i) { gload_lds16(sp[i], dp[i]); sp[i] += sstep; }
    __syncthreads();  // staging landed (vmcnt drained by barrier)

    if (s <= sD) {
      // S^T: 128 keys x 16 q
      f32x4 sc[2][4] = {};
#pragma unroll
      for (int h = 0; h < 2; ++h)
#pragma unroll
        for (int mt = 0; mt < 4; ++mt)
#pragma unroll
          for (int ks = 0; ks < 2; ++ks) {
            bf16x8 kf = load_frag(lK + h * 4096 + mt * 1024 + (ks * 4 + quad) * 128 + ln * 8);
            sc[h][mt] = mfma16(kf, qf[ks], sc[h][mt]);
          }
      // causal mask only on this wave's diagonal super-tile (covers phantom half too)
      if (s == sD) {
#pragma unroll
        for (int h = 0; h < 2; ++h)
#pragma unroll
          for (int mt = 0; mt < 4; ++mt) {
            int key0 = (2 * s + h) * 64 + mt * 16 + quad * 4;
#pragma unroll
            for (int r = 0; r < 4; ++r)
              if (key0 + r > qq) sc[h][mt][r] = -1e30f;
          }
      }
      // merged online softmax over 32 in-lane scores + quad butterfly
      float mloc = sc[0][0][0];
#pragma unroll
      for (int h = 0; h < 2; ++h)
#pragma unroll
        for (int mt = 0; mt < 4; ++mt)
#pragma unroll
          for (int r = 0; r < 4; ++r) mloc = fmaxf(mloc, sc[h][mt][r]);
      mloc = fmaxf(mloc, __shfl_xor(mloc, 16));
      mloc = fmaxf(mloc, __shfl_xor(mloc, 32));
      float mnew = fmaxf(m_r, mloc);
      float alpha = __builtin_amdgcn_exp2f((m_r - mnew) * SC);
      float nmsc = -mnew * SC;
      float sum = 0.f;
#pragma unroll
      for (int h = 0; h < 2; ++h)
#pragma unroll
        for (int mt = 0; mt < 4; ++mt)
#pragma unroll
          for (int r = 0; r < 4; ++r) {
            float p = __builtin_amdgcn_exp2f(__builtin_fmaf(sc[h][mt][r], SC, nmsc));
            sc[h][mt][r] = p;
            sum += p;
          }
      sum += __shfl_xor(sum, 16);
      sum += __shfl_xor(sum, 32);
      l_r = l_r * alpha + sum;
      m_r = mnew;
#pragma unroll
      for (int dt = 0; dt < 4; ++dt) o[dt] *= alpha;

      // per half: P -> wave-private swizzled LDS, then O^T += V^T·P^T
#pragma unroll
      for (int h = 0; h < 2; ++h) {
#pragma unroll
        for (int mt = 0; mt < 4; ++mt) {
          uint2 pk;
          pk.x = cvt_pk_bf16(sc[h][mt][0], sc[h][mt][1]);
          pk.y = cvt_pk_bf16(sc[h][mt][2], sc[h][mt][3]);
          int addr = ln * 64 + (((mt * 2 + (quad >> 1)) ^ (ln & 7)) * 8) + (quad & 1) * 4;
          *(uint2*)(lPw + addr) = pk;
        }
        bf16x8 pf[2];
#pragma unroll
        for (int ks = 0; ks < 2; ++ks)
          pf[ks] = load_frag(lPw + ln * 64 + (((ks * 4 + quad) ^ (ln & 7)) * 8));
#pragma unroll
        for (int dt = 0; dt < 4; ++dt)
#pragma unroll
          for (int ks = 0; ks < 2; ++ks) {
            bf16x8 av = load_frag(lV + h * 4096 + dt * 1024 + (ks * 4 + quad) * 128 + ln * 8);
            o[dt] = mfma16(av, pf[ks], o[dt]);
          }
      }
    }
  }

  // epilogue: normalize, transpose O^T -> [q][d] via wave-private LDS, 16B stores
  float inv = 1.f / l_r;
#pragma unroll
  for (int dt = 0; dt < 4; ++dt) {
    uint2 pk;
    pk.x = cvt_pk_bf16(o[dt][0] * inv, o[dt][1] * inv);
    pk.y = cvt_pk_bf16(o[dt][2] * inv, o[dt][3] * inv);
    *(uint2*)(lPw + ln * 72 + dt * 16 + quad * 4) = pk;
  }
  const int b = bh >> 4, h2 = bh & 15;
#pragma unroll
  for (int i = 0; i < 2; ++i) {
    int c = lane + i * 64;
    int qq2 = c >> 3, dg = c & 7;
    uint4 val = *(const uint4*)(lPw + qq2 * 72 + dg * 8);
    *(uint4*)(Ob + ((size_t)b * SEQ + q0w + qq2) * 1024 + h2 * 64 + dg * 8) = val;
  }
}

// ---------------- GEMM 2: out = values @ W_out + b (fp32 out) ----------------
// 128(M) x 64(N) tile, BK=32, async double buffer (r9-proven pattern), grid 16x32=512.

__global__ __launch_bounds__(256, 3) void gemm_out(const u16* __restrict__ A,   // Ob [4096][1024]
                                                   const u16* __restrict__ Bt,  // WoutT [1024][1024]
                                                   const float* __restrict__ bias,
                                                   float* __restrict__ out) {
  __shared__ u16 lA0[128 * 32], lB0[64 * 32];
  __shared__ u16 lA1[128 * 32], lB1[64 * 32];
  const int tid = threadIdx.x;
  const int wave = tid >> 6, lane = tid & 63, ln = lane & 15, quad = lane >> 4;
  const int n0 = blockIdx.x * 64, m0 = blockIdx.y * 128;
  f32x4 acc[2][4] = {};

  auto issue = [&](u16* dA, u16* dB, int k0) {
#pragma unroll
    for (int i = 0; i < 3; ++i) {
      int c = wave * 3 + i;  // 12 chunks: 8 A + 4 B
      if (c < 8) {
        gload_lds16(A + (size_t)(m0 + c * 16 + ln) * 1024 + k0 + quad * 8, dA + c * 512);
      } else {
        int cc = c - 8;
        gload_lds16(Bt + (size_t)(n0 + cc * 16 + ln) * 1024 + k0 + quad * 8, dB + cc * 512);
      }
    }
  };
  auto compute = [&](const u16* sA, const u16* sB) {
    bf16x8 a[2], b[4];
#pragma unroll
    for (int i = 0; i < 2; ++i)
      a[i] = load_frag(sA + (wave * 2 + i) * 512 + quad * 128 + ln * 8);
#pragma unroll
    for (int i = 0; i < 4; ++i)
      b[i] = load_frag(sB + i * 512 + quad * 128 + ln * 8);
#pragma unroll
    for (int mt = 0; mt < 2; ++mt)
#pragma unroll
      for (int nt = 0; nt < 4; ++nt) acc[mt][nt] = mfma16(a[mt], b[nt], acc[mt][nt]);
  };

  issue(lA0, lB0, 0);
  for (int p = 0; p < 15; ++p) {
    asm volatile("s_barrier" ::: "memory");
    issue(lA1, lB1, (2 * p + 1) * 32);
    asm volatile("s_waitcnt vmcnt(3)" ::: "memory");
    asm volatile("s_barrier" ::: "memory");
    compute(lA0, lB0);
    asm volatile("s_barrier" ::: "memory");
    issue(lA0, lB0, (2 * p + 2) * 32);
    asm volatile("s_waitcnt vmcnt(3)" ::: "memory");
    asm volatile("s_barrier" ::: "memory");
    compute(lA1, lB1);
  }
  asm volatile("s_barrier" ::: "memory");
  issue(lA1, lB1, 31 * 32);
  asm volatile("s_waitcnt vmcnt(3)" ::: "memory");
  asm volatile("s_barrier" ::: "memory");
  compute(lA0, lB0);
  asm volatile("s_waitcnt vmcnt(0)" ::: "memory");
  asm volatile("s_barrier" ::: "memory");
  compute(lA1, lB1);

#pragma unroll
  for (int mt = 0; mt < 2; ++mt) {
    int row = m0 + wave * 32 + mt * 16 + quad * 4;
#pragma unroll
    for (int nt = 0; nt < 4; ++nt) {
      int col = n0 + nt * 16 + ln;
      float bv = bias[col];
#pragma unroll
      for (int r = 0; r < 4; ++r)
        out[(size_t)(row + r) * 1024 + col] = acc[mt][nt][r] + bv;
    }
  }
}

// ---------------- launcher ----------------

extern "C" void kernel_launch(void* const* d_in, const int* in_sizes, int n_in,
                              void* d_out, int out_size, void* d_ws, size_t ws_size,
                              hipStream_t stream) {
  const float* x = (const float*)d_in[0];
  const float* W_qkv = (const float*)d_in[1];
  const float* b_qkv = (const float*)d_in[2];
  const float* W_out = (const float*)d_in[3];
  const float* b_out = (const float*)d_in[4];
  float* out = (float*)d_out;

  char* ws = (char*)d_ws;
  const size_t SZ_XB = (size_t)ROWS * D_MODEL * 2;            // 8 MiB
  const size_t SZ_WQKVT = (size_t)3 * D_MODEL * D_MODEL * 2;  // 6 MiB
  const size_t SZ_WOUTT = (size_t)D_MODEL * D_MODEL * 2;      // 2 MiB
  const size_t SZ_HEADS = (size_t)BATCH * NUM_HEADS * SEQ * HEAD_DIM * 2;  // 8 MiB
  u16* xb = (u16*)(ws);
  u16* WqkvT = (u16*)(ws + SZ_XB);
  u16* WoutT = (u16*)(ws + SZ_XB + SZ_WQKVT);
  u16* Qb = (u16*)(ws + SZ_XB + SZ_WQKVT + SZ_WOUTT);
  u16* Kb = (u16*)(ws + SZ_XB + SZ_WQKVT + SZ_WOUTT + SZ_HEADS);
  u16* Vt = (u16*)(ws + SZ_XB + SZ_WQKVT + SZ_WOUTT + 2 * SZ_HEADS);
  u16* Ob = (u16*)(ws + SZ_XB + SZ_WQKVT + SZ_WOUTT + 3 * SZ_HEADS);

  prep_kernel<<<dim3(8192), dim3(256), 0, stream>>>(x, xb, W_qkv, WqkvT, W_out, WoutT);
  gemm_qkv<<<dim3(3 * D_MODEL / 256, ROWS / 256), dim3(512), 0, stream>>>(xb, WqkvT, b_qkv,
                                                                          Qb, Kb, Vt);
  attn_kernel<<<dim3(SEQ / 128, BATCH * NUM_HEADS), dim3(512), 0, stream>>>(Qb, Kb, Vt, Ob);
  gemm_out<<<dim3(D_MODEL / 64, ROWS / 128), dim3(256), 0, stream>>>(Ob, WoutT, b_out, out);
}

// Round 2
// 204.337 us; speedup vs baseline: 1.0427x; 1.0427x over previous
//
#include <hip/hip_runtime.h>
#include <hip/hip_bf16.h>

#define D_MODEL 1024
#define NUM_HEADS 16
#define HEAD_DIM 64
#define SEQ 2048
#define BATCH 2
#define ROWS (BATCH * SEQ)  // 4096

typedef unsigned short u16;
typedef __bf16 bf16x8 __attribute__((ext_vector_type(8)));
typedef float f32x4 __attribute__((ext_vector_type(4)));

__device__ inline u16 f2bfu(float f) {
  // RNE float->bf16
  unsigned u = __float_as_uint(f);
  unsigned r = (u + 0x7fffu + ((u >> 16) & 1u)) >> 16;
  return (u16)r;
}

// packed f32x2 -> bf16x2 (one v_cvt_pk_bf16_f32 on gfx950; RNE fallback otherwise)
__device__ inline unsigned cvt_pk_bf16(float a, float b) {
#if __has_builtin(__builtin_amdgcn_cvt_pk_bf16_f32)
  auto r = __builtin_amdgcn_cvt_pk_bf16_f32(a, b);
  unsigned u;
  __builtin_memcpy(&u, &r, 4);
  return u;
#else
  return (unsigned)f2bfu(a) | ((unsigned)f2bfu(b) << 16);
#endif
}

__device__ inline f32x4 mfma16(bf16x8 a, bf16x8 b, f32x4 c) {
  return __builtin_amdgcn_mfma_f32_16x16x32_bf16(a, b, c, 0, 0, 0);
}

__device__ inline bf16x8 load_frag(const u16* p) {
  union { uint4 v; bf16x8 f; } u;
  u.v = *(const uint4*)p;
  return u.f;
}

// async global->LDS, 16B per lane; LDS dest = wave-uniform base + lane*16
__device__ inline void gload_lds16(const u16* g, u16* l) {
  __builtin_amdgcn_global_load_lds((const __attribute__((address_space(1))) void*)g,
                                   (__attribute__((address_space(3))) void*)l, 16, 0, 0);
}

// ---------------- fused prep: cvt x + transpose-cvt both weight matrices ----------------
// grid: [0,4096) cvt_x chunks; [4096,7168) W_qkv 32x32 tiles; [7168,8192) W_out tiles.

__global__ __launch_bounds__(256) void prep_kernel(const float* __restrict__ x,
                                                   u16* __restrict__ xb,
                                                   const float* __restrict__ Wq,
                                                   u16* __restrict__ WqT,
                                                   const float* __restrict__ Wo,
                                                   u16* __restrict__ WoT) {
  __shared__ float t[32][33];
  const int bid = blockIdx.x;
  if (bid < 4096) {
    int i = bid * 256 + threadIdx.x;  // 4 floats each
    float4 v = ((const float4*)x)[i];
    uint2 o;
    o.x = cvt_pk_bf16(v.x, v.y);
    o.y = cvt_pk_bf16(v.z, v.w);
    ((uint2*)xb)[i] = o;
    return;
  }
  const float* W;
  u16* Wt;
  int N, tIdx;
  if (bid < 4096 + 3072) { W = Wq; Wt = WqT; N = 3072; tIdx = bid - 4096; }
  else                   { W = Wo; Wt = WoT; N = 1024; tIdx = bid - 7168; }
  const int k0 = (tIdx & 31) * 32, n0 = (tIdx >> 5) * 32;
  const int c = threadIdx.x & 31, r8 = threadIdx.x >> 5;
#pragma unroll
  for (int i = 0; i < 4; i++) {
    int r = r8 + i * 8;
    t[r][c] = W[(size_t)(k0 + r) * N + n0 + c];
  }
  __syncthreads();
#pragma unroll
  for (int i = 0; i < 4; i++) {
    int r = r8 + i * 8;
    Wt[(size_t)(n0 + r) * 1024 + k0 + c] = f2bfu(t[c][r]);
  }
}

// ---------------- GEMM 1: qkv = x @ W_qkv + b -> Qb/Kb [bh][s][64], Vt [bh][d][s] ----------------
// 128x128 tile, BK=32, explicit double buffer with raw s_barrier + s_waitcnt vmcnt(4).
// [validated r9: 86 -> <62 us]
// XCD supertile swizzle: 768 blocks -> 8 regions (8 Mpanels x 12 Npanels = 96 tiles).
// Consecutive dispatch ids round-robin across XCDs, so region r lands on XCD r:
// each XCD's resident blocks touch A 2MB + B 3MB ~= L2-resident (vs 14MB unswizzled).

__global__ __launch_bounds__(256, 3) void gemm_qkv(const u16* __restrict__ A,   // xb [4096][1024]
                                                   const u16* __restrict__ Bt,  // WqkvT [3072][1024]
                                                   const float* __restrict__ bias,
                                                   u16* __restrict__ Qb, u16* __restrict__ Kb,
                                                   u16* __restrict__ Vt) {
  __shared__ u16 lA0[128 * 32], lB0[128 * 32];  // 8 KB each
  __shared__ u16 lA1[128 * 32], lB1[128 * 32];
  const int tid = threadIdx.x;
  const int wave = tid >> 6, lane = tid & 63, ln = lane & 15, quad = lane >> 4;
  const int lin = blockIdx.y * 24 + blockIdx.x;
  const int reg = lin & 7, idx = lin >> 3;      // 8 regions x 96 tiles
  const int mr = idx / 12, nr = idx - mr * 12;  // region = 8 Mpanels x 12 Npanels
  const int m0 = ((reg >> 1) * 8 + mr) * 128;
  const int n0 = (((reg & 1) * 12) + nr) * 128;
  const int wm = (wave & 1) * 64, wn = (wave >> 1) * 64;
  f32x4 acc[4][4] = {};

  auto issue = [&](u16* dA, u16* dB, int k0) {
#pragma unroll
    for (int i = 0; i < 2; ++i) {
      int rb = wave * 2 + i;  // 0..7
      gload_lds16(A + (size_t)(m0 + rb * 16 + ln) * 1024 + k0 + quad * 8, dA + rb * 512);
      gload_lds16(Bt + (size_t)(n0 + rb * 16 + ln) * 1024 + k0 + quad * 8, dB + rb * 512);
    }
  };
  auto compute = [&](const u16* sA, const u16* sB) {
    bf16x8 a[4], b[4];
#pragma unroll
    for (int i = 0; i < 4; ++i) {
      a[i] = load_frag(sA + (wm / 16 + i) * 512 + quad * 128 + ln * 8);
      b[i] = load_frag(sB + (wn / 16 + i) * 512 + quad * 128 + ln * 8);
    }
#pragma unroll
    for (int mt = 0; mt < 4; ++mt)
#pragma unroll
      for (int nt = 0; nt < 4; ++nt) acc[mt][nt] = mfma16(a[mt], b[nt], acc[mt][nt]);
  };

  issue(lA0, lB0, 0);  // prologue: tile 0 -> buf0
  for (int p = 0; p < 15; ++p) {
    asm volatile("s_barrier" ::: "memory");
    issue(lA1, lB1, (2 * p + 1) * 32);
    asm volatile("s_waitcnt vmcnt(4)" ::: "memory");
    asm volatile("s_barrier" ::: "memory");
    compute(lA0, lB0);
    asm volatile("s_barrier" ::: "memory");
    issue(lA0, lB0, (2 * p + 2) * 32);
    asm volatile("s_waitcnt vmcnt(4)" ::: "memory");
    asm volatile("s_barrier" ::: "memory");
    compute(lA1, lB1);
  }
  asm volatile("s_barrier" ::: "memory");
  issue(lA1, lB1, 31 * 32);
  asm volatile("s_waitcnt vmcnt(4)" ::: "memory");
  asm volatile("s_barrier" ::: "memory");
  compute(lA0, lB0);
  asm volatile("s_waitcnt vmcnt(0)" ::: "memory");
  asm volatile("s_barrier" ::: "memory");
  compute(lA1, lB1);

#pragma unroll
  for (int mt = 0; mt < 4; ++mt) {
    int row = m0 + wm + mt * 16 + quad * 4;
    int bb = row >> 11, s0 = row & 2047;
#pragma unroll
    for (int nt = 0; nt < 4; ++nt) {
      int col = n0 + wn + nt * 16 + ln;
      float bv = bias[col];
      int h = col / 192, rem = col - h * 192, t3 = rem >> 6, d = rem & 63;
      int bh = bb * NUM_HEADS + h;
      if (t3 == 2) {  // V -> transposed layout [bh][d][s], 4 consecutive s packed
        uint2 pk;
        pk.x = cvt_pk_bf16(acc[mt][nt][0] + bv, acc[mt][nt][1] + bv);
        pk.y = cvt_pk_bf16(acc[mt][nt][2] + bv, acc[mt][nt][3] + bv);
        *(uint2*)(Vt + ((size_t)bh * 64 + d) * SEQ + s0) = pk;
      } else {
        u16* dst = (t3 == 0) ? Qb : Kb;
#pragma unroll
        for (int r = 0; r < 4; ++r)
          dst[((size_t)bh * SEQ + s0 + r) * 64 + d] = f2bfu(acc[mt][nt][r] + bv);
      }
    }
  }
}

// ---------------- flash attention, balanced-pair blocks + 128-key super-tiles ----------------
// Block j (0..15): q-tiles lo=j, hi=31-j. 8 waves: 0-3 own lo rows, 4-7 own hi rows.
// Per super-iter: stage TWO 64-key tiles (K 16KB + Vt 16KB, single-buffered,
// global_load_lds w16, 4 chunks/wave), then ONE merged online-softmax update over
// 128 keys (halves softmax passes, barriers, alpha-rescales vs 64-key tiles).
// Phantom tail half is staged in-bounds (kt<=31) and masked to -1e30.
// XCD swizzle: each XCD owns 4 consecutive heads x all 16 j-blocks, so one head's
// 512KB K/V is fetched into that XCD's L2 once and reused by 16 blocks.

__global__ __launch_bounds__(512) void attn_kernel(const u16* __restrict__ Qb,
                                                   const u16* __restrict__ Kb,
                                                   const u16* __restrict__ Vt,
                                                   u16* __restrict__ Ob) {
  __shared__ u16 lK[2 * 64 * 64];  // two 64-key halves, fragment order (8 KB each)
  __shared__ u16 lV[2 * 64 * 64];
  __shared__ u16 lP[8][1152];      // per-wave P swizzle (1024 used) + epilogue (16x72)
  const int tid = threadIdx.x;
  const int wave = tid >> 6, lane = tid & 63;
  const int ln = lane & 15, quad = lane >> 4;
  const int lin = blockIdx.y * 16 + blockIdx.x;   // 512 blocks
  const int xreg = lin & 7, xidx = lin >> 3;      // XCD region, 64 blocks each
  const int j = xidx & 15;                        // q-block 0..15 (j=0 heaviest, early)
  const int bh = xreg * 4 + (xidx >> 4);          // 4 consecutive heads per XCD
  const int lo = j, hi = 31 - j;
  const int myt = (wave < 4) ? lo : hi;
  const int q0w = myt * 64 + (wave & 3) * 16;  // this wave's 16-row base
  const int sD = myt >> 1;                     // this wave's diagonal super-tile
  const int nsup = (hi + 2) >> 1;              // block-wide super-iteration count
  const u16* Qg = Qb + (size_t)bh * SEQ * 64;
  const u16* Kg = Kb + (size_t)bh * SEQ * 64;
  const u16* Vg = Vt + (size_t)bh * 64 * SEQ;
  u16* lPw = lP[wave];

  // Q B-frags, loaded once
  bf16x8 qf[2];
#pragma unroll
  for (int ks = 0; ks < 2; ++ks)
    qf[ks] = load_frag(Qg + (size_t)(q0w + ln) * 64 + ks * 32 + quad * 8);

  // staging: 32 chunks of 1KB (16 K + 16 V), wave w owns c = w*4..w*4+3
  // (waves 0-3 all-K, waves 4-7 all-V -> uniform stride per wave)
  const u16* sp[4];
  u16* dp[4];
  const int sstep = (wave < 4) ? 128 * 64 : 128;  // K: +128 rows; V: +128 cols
#pragma unroll
  for (int i = 0; i < 4; ++i) {
    int c = wave * 4 + i;
    if (c < 16) {
      int half = c >> 3, cc = c & 7, rb = cc >> 1, kgh = cc & 1;
      sp[i] = Kg + (size_t)(half * 64 + rb * 16 + ln) * 64 + (kgh * 4 + quad) * 8;
      dp[i] = lK + half * 4096 + rb * 1024 + kgh * 512;
    } else {
      int c2 = c - 16, half = c2 >> 3, cc = c2 & 7, rb = cc >> 1, kgh = cc & 1;
      sp[i] = Vg + (size_t)(rb * 16 + ln) * SEQ + half * 64 + (kgh * 4 + quad) * 8;
      dp[i] = lV + half * 4096 + rb * 1024 + kgh * 512;
    }
  }

  f32x4 o[4] = {};     // O^T: row d=dt*16+quad*4+r, col q=ln
  float m_r = -1e30f;  // raw-score domain
  float l_r = 0.f;
  const float SC = 0.18033688011112042f;  // log2(e) / sqrt(64)
  const int qq = q0w + ln;

  for (int s = 0; s < nsup; ++s) {
    __syncthreads();  // previous super-tile fully consumed
#pragma unroll
    for (int i = 0; i < 4; ++i) { gload_lds16(sp[i], dp[i]); sp[i] += sstep; }
    __syncthreads();  // staging landed (vmcnt drained by barrier)

    if (s <= sD) {
      // S^T: 128 keys x 16 q
      f32x4 sc[2][4] = {};
#pragma unroll
      for (int h = 0; h < 2; ++h)
#pragma unroll
        for (int mt = 0; mt < 4; ++mt)
#pragma unroll
          for (int ks = 0; ks < 2; ++ks) {
            bf16x8 kf = load_frag(lK + h * 4096 + mt * 1024 + (ks * 4 + quad) * 128 + ln * 8);
            sc[h][mt] = mfma16(kf, qf[ks], sc[h][mt]);
          }
      // causal mask only on this wave's diagonal super-tile (covers phantom half too)
      if (s == sD) {
#pragma unroll
        for (int h = 0; h < 2; ++h)
#pragma unroll
          for (int mt = 0; mt < 4; ++mt) {
            int key0 = (2 * s + h) * 64 + mt * 16 + quad * 4;
#pragma unroll
            for (int r = 0; r < 4; ++r)
              if (key0 + r > qq) sc[h][mt][r] = -1e30f;
          }
      }
      // merged online softmax over 32 in-lane scores + quad butterfly
      float mloc = sc[0][0][0];
#pragma unroll
      for (int h = 0; h < 2; ++h)
#pragma unroll
        for (int mt = 0; mt < 4; ++mt)
#pragma unroll
          for (int r = 0; r < 4; ++r) mloc = fmaxf(mloc, sc[h][mt][r]);
      mloc = fmaxf(mloc, __shfl_xor(mloc, 16));
      mloc = fmaxf(mloc, __shfl_xor(mloc, 32));
      float mnew = fmaxf(m_r, mloc);
      float alpha = __builtin_amdgcn_exp2f((m_r - mnew) * SC);
      float nmsc = -mnew * SC;
      float sum = 0.f;
#pragma unroll
      for (int h = 0; h < 2; ++h)
#pragma unroll
        for (int mt = 0; mt < 4; ++mt)
#pragma unroll
          for (int r = 0; r < 4; ++r) {
            float p = __builtin_amdgcn_exp2f(__builtin_fmaf(sc[h][mt][r], SC, nmsc));
            sc[h][mt][r] = p;
            sum += p;
          }
      sum += __shfl_xor(sum, 16);
      sum += __shfl_xor(sum, 32);
      l_r = l_r * alpha + sum;
      m_r = mnew;
#pragma unroll
      for (int dt = 0; dt < 4; ++dt) o[dt] *= alpha;

      // per half: P -> wave-private swizzled LDS, then O^T += V^T·P^T
#pragma unroll
      for (int h = 0; h < 2; ++h) {
#pragma unroll
        for (int mt = 0; mt < 4; ++mt) {
          uint2 pk;
          pk.x = cvt_pk_bf16(sc[h][mt][0], sc[h][mt][1]);
          pk.y = cvt_pk_bf16(sc[h][mt][2], sc[h][mt][3]);
          int addr = ln * 64 + (((mt * 2 + (quad >> 1)) ^ (ln & 7)) * 8) + (quad & 1) * 4;
          *(uint2*)(lPw + addr) = pk;
        }
        bf16x8 pf[2];
#pragma unroll
        for (int ks = 0; ks < 2; ++ks)
          pf[ks] = load_frag(lPw + ln * 64 + (((ks * 4 + quad) ^ (ln & 7)) * 8));
#pragma unroll
        for (int dt = 0; dt < 4; ++dt)
#pragma unroll
          for (int ks = 0; ks < 2; ++ks) {
            bf16x8 av = load_frag(lV + h * 4096 + dt * 1024 + (ks * 4 + quad) * 128 + ln * 8);
            o[dt] = mfma16(av, pf[ks], o[dt]);
          }
      }
    }
  }

  // epilogue: normalize, transpose O^T -> [q][d] via wave-private LDS, 16B stores
  float inv = 1.f / l_r;
#pragma unroll
  for (int dt = 0; dt < 4; ++dt) {
    uint2 pk;
    pk.x = cvt_pk_bf16(o[dt][0] * inv, o[dt][1] * inv);
    pk.y = cvt_pk_bf16(o[dt][2] * inv, o[dt][3] * inv);
    *(uint2*)(lPw + ln * 72 + dt * 16 + quad * 4) = pk;
  }
  const int b = bh >> 4, h2 = bh & 15;
#pragma unroll
  for (int i = 0; i < 2; ++i) {
    int c = lane + i * 64;
    int qq2 = c >> 3, dg = c & 7;
    uint4 val = *(const uint4*)(lPw + qq2 * 72 + dg * 8);
    *(uint4*)(Ob + ((size_t)b * SEQ + q0w + qq2) * 1024 + h2 * 64 + dg * 8) = val;
  }
}

// ---------------- GEMM 2: out = values @ W_out + b (fp32 out) ----------------
// 128(M) x 64(N) tile, BK=32, async double buffer (r9-proven pattern), grid 16x32=512.
// XCD supertile swizzle: 8 regions of 8 Mpanels x 8 Npanels (A 2MB + B 1MB per XCD).

__global__ __launch_bounds__(256, 3) void gemm_out(const u16* __restrict__ A,   // Ob [4096][1024]
                                                   const u16* __restrict__ Bt,  // WoutT [1024][1024]
                                                   const float* __restrict__ bias,
                                                   float* __restrict__ out) {
  __shared__ u16 lA0[128 * 32], lB0[64 * 32];
  __shared__ u16 lA1[128 * 32], lB1[64 * 32];
  const int tid = threadIdx.x;
  const int wave = tid >> 6, lane = tid & 63, ln = lane & 15, quad = lane >> 4;
  const int lin = blockIdx.y * 16 + blockIdx.x;
  const int reg = lin & 7, idx = lin >> 3;  // 8 regions x 64 tiles
  const int mr = idx >> 3, nr = idx & 7;    // region = 8 Mpanels x 8 Npanels
  const int m0 = ((reg >> 1) * 8 + mr) * 128;
  const int n0 = (((reg & 1) * 8) + nr) * 64;
  f32x4 acc[2][4] = {};

  auto issue = [&](u16* dA, u16* dB, int k0) {
#pragma unroll
    for (int i = 0; i < 3; ++i) {
      int c = wave * 3 + i;  // 12 chunks: 8 A + 4 B
      if (c < 8) {
        gload_lds16(A + (size_t)(m0 + c * 16 + ln) * 1024 + k0 + quad * 8, dA + c * 512);
      } else {
        int cc = c - 8;
        gload_lds16(Bt + (size_t)(n0 + cc * 16 + ln) * 1024 + k0 + quad * 8, dB + cc * 512);
      }
    }
  };
  auto compute = [&](const u16* sA, const u16* sB) {
    bf16x8 a[2], b[4];
#pragma unroll
    for (int i = 0; i < 2; ++i)
      a[i] = load_frag(sA + (wave * 2 + i) * 512 + quad * 128 + ln * 8);
#pragma unroll
    for (int i = 0; i < 4; ++i)
      b[i] = load_frag(sB + i * 512 + quad * 128 + ln * 8);
#pragma unroll
    for (int mt = 0; mt < 2; ++mt)
#pragma unroll
      for (int nt = 0; nt < 4; ++nt) acc[mt][nt] = mfma16(a[mt], b[nt], acc[mt][nt]);
  };

  issue(lA0, lB0, 0);
  for (int p = 0; p < 15; ++p) {
    asm volatile("s_barrier" ::: "memory");
    issue(lA1, lB1, (2 * p + 1) * 32);
    asm volatile("s_waitcnt vmcnt(3)" ::: "memory");
    asm volatile("s_barrier" ::: "memory");
    compute(lA0, lB0);
    asm volatile("s_barrier" ::: "memory");
    issue(lA0, lB0, (2 * p + 2) * 32);
    asm volatile("s_waitcnt vmcnt(3)" ::: "memory");
    asm volatile("s_barrier" ::: "memory");
    compute(lA1, lB1);
  }
  asm volatile("s_barrier" ::: "memory");
  issue(lA1, lB1, 31 * 32);
  asm volatile("s_waitcnt vmcnt(3)" ::: "memory");
  asm volatile("s_barrier" ::: "memory");
  compute(lA0, lB0);
  asm volatile("s_waitcnt vmcnt(0)" ::: "memory");
  asm volatile("s_barrier" ::: "memory");
  compute(lA1, lB1);

#pragma unroll
  for (int mt = 0; mt < 2; ++mt) {
    int row = m0 + wave * 32 + mt * 16 + quad * 4;
#pragma unroll
    for (int nt = 0; nt < 4; ++nt) {
      int col = n0 + nt * 16 + ln;
      float bv = bias[col];
#pragma unroll
      for (int r = 0; r < 4; ++r)
        out[(size_t)(row + r) * 1024 + col] = acc[mt][nt][r] + bv;
    }
  }
}

// ---------------- launcher ----------------

extern "C" void kernel_launch(void* const* d_in, const int* in_sizes, int n_in,
                              void* d_out, int out_size, void* d_ws, size_t ws_size,
                              hipStream_t stream) {
  const float* x = (const float*)d_in[0];
  const float* W_qkv = (const float*)d_in[1];
  const float* b_qkv = (const float*)d_in[2];
  const float* W_out = (const float*)d_in[3];
  const float* b_out = (const float*)d_in[4];
  float* out = (float*)d_out;

  char* ws = (char*)d_ws;
  const size_t SZ_XB = (size_t)ROWS * D_MODEL * 2;            // 8 MiB
  const size_t SZ_WQKVT = (size_t)3 * D_MODEL * D_MODEL * 2;  // 6 MiB
  const size_t SZ_WOUTT = (size_t)D_MODEL * D_MODEL * 2;      // 2 MiB
  const size_t SZ_HEADS = (size_t)BATCH * NUM_HEADS * SEQ * HEAD_DIM * 2;  // 8 MiB
  u16* xb = (u16*)(ws);
  u16* WqkvT = (u16*)(ws + SZ_XB);
  u16* WoutT = (u16*)(ws + SZ_XB + SZ_WQKVT);
  u16* Qb = (u16*)(ws + SZ_XB + SZ_WQKVT + SZ_WOUTT);
  u16* Kb = (u16*)(ws + SZ_XB + SZ_WQKVT + SZ_WOUTT + SZ_HEADS);
  u16* Vt = (u16*)(ws + SZ_XB + SZ_WQKVT + SZ_WOUTT + 2 * SZ_HEADS);
  u16* Ob = (u16*)(ws + SZ_XB + SZ_WQKVT + SZ_WOUTT + 3 * SZ_HEADS);

  prep_kernel<<<dim3(8192), dim3(256), 0, stream>>>(x, xb, W_qkv, WqkvT, W_out, WoutT);
  gemm_qkv<<<dim3(3 * D_MODEL / 128, ROWS / 128), dim3(256), 0, stream>>>(xb, WqkvT, b_qkv,
                                                                          Qb, Kb, Vt);
  attn_kernel<<<dim3(SEQ / 128, BATCH * NUM_HEADS), dim3(512), 0, stream>>>(Qb, Kb, Vt, Ob);
  gemm_out<<<dim3(D_MODEL / 64, ROWS / 128), dim3(256), 0, stream>>>(Ob, WoutT, b_out, out);
}

// Round 3
// 202.195 us; speedup vs baseline: 1.0538x; 1.0106x over previous
//
#include <hip/hip_runtime.h>
#include <hip/hip_bf16.h>

#define D_MODEL 1024
#define NUM_HEADS 16
#define HEAD_DIM 64
#define SEQ 2048
#define BATCH 2
#define ROWS (BATCH * SEQ)  // 4096

typedef unsigned short u16;
typedef __bf16 bf16x8 __attribute__((ext_vector_type(8)));
typedef float f32x4 __attribute__((ext_vector_type(4)));

__device__ inline u16 f2bfu(float f) {
  // RNE float->bf16
  unsigned u = __float_as_uint(f);
  unsigned r = (u + 0x7fffu + ((u >> 16) & 1u)) >> 16;
  return (u16)r;
}

// packed f32x2 -> bf16x2 (one v_cvt_pk_bf16_f32 on gfx950; RNE fallback otherwise)
__device__ inline unsigned cvt_pk_bf16(float a, float b) {
#if __has_builtin(__builtin_amdgcn_cvt_pk_bf16_f32)
  auto r = __builtin_amdgcn_cvt_pk_bf16_f32(a, b);
  unsigned u;
  __builtin_memcpy(&u, &r, 4);
  return u;
#else
  return (unsigned)f2bfu(a) | ((unsigned)f2bfu(b) << 16);
#endif
}

__device__ inline f32x4 mfma16(bf16x8 a, bf16x8 b, f32x4 c) {
  return __builtin_amdgcn_mfma_f32_16x16x32_bf16(a, b, c, 0, 0, 0);
}

__device__ inline bf16x8 load_frag(const u16* p) {
  union { uint4 v; bf16x8 f; } u;
  u.v = *(const uint4*)p;
  return u.f;
}

// async global->LDS, 16B per lane; LDS dest = wave-uniform base + lane*16
__device__ inline void gload_lds16(const u16* g, u16* l) {
  __builtin_amdgcn_global_load_lds((const __attribute__((address_space(1))) void*)g,
                                   (__attribute__((address_space(3))) void*)l, 16, 0, 0);
}

// ---------------- fused prep: cvt x + transpose-cvt both weight matrices ----------------
// grid: [0,4096) cvt_x chunks; [4096,7168) W_qkv 32x32 tiles; [7168,8192) W_out tiles.

__global__ __launch_bounds__(256) void prep_kernel(const float* __restrict__ x,
                                                   u16* __restrict__ xb,
                                                   const float* __restrict__ Wq,
                                                   u16* __restrict__ WqT,
                                                   const float* __restrict__ Wo,
                                                   u16* __restrict__ WoT) {
  __shared__ float t[32][33];
  const int bid = blockIdx.x;
  if (bid < 4096) {
    int i = bid * 256 + threadIdx.x;  // 4 floats each
    float4 v = ((const float4*)x)[i];
    uint2 o;
    o.x = cvt_pk_bf16(v.x, v.y);
    o.y = cvt_pk_bf16(v.z, v.w);
    ((uint2*)xb)[i] = o;
    return;
  }
  const float* W;
  u16* Wt;
  int N, tIdx;
  if (bid < 4096 + 3072) { W = Wq; Wt = WqT; N = 3072; tIdx = bid - 4096; }
  else                   { W = Wo; Wt = WoT; N = 1024; tIdx = bid - 7168; }
  const int k0 = (tIdx & 31) * 32, n0 = (tIdx >> 5) * 32;
  const int c = threadIdx.x & 31, r8 = threadIdx.x >> 5;
#pragma unroll
  for (int i = 0; i < 4; i++) {
    int r = r8 + i * 8;
    t[r][c] = W[(size_t)(k0 + r) * N + n0 + c];
  }
  __syncthreads();
#pragma unroll
  for (int i = 0; i < 4; i++) {
    int r = r8 + i * 8;
    Wt[(size_t)(n0 + r) * 1024 + k0 + c] = f2bfu(t[c][r]);
  }
}

// ---------------- GEMM 1: qkv = x @ W_qkv + b -> Qb/Kb [bh][s][64], Vt [bh][d][s] ----------------
// 128x128 tile, BK=32. 3-slot LDS rotation, 2 tiles in flight, ONE barrier + one
// counted vmcnt(4) per K-step (T3/T4 minimum recipe grafted on the validated r9 core):
//   iter t: issue(tile t+2 -> slot (t+2)%3); compute(slot t%3); vmcnt(4); s_barrier
// vmcnt(4): after issue, 8 loads outstanding per wave (t+1's 4 + t+2's 4); waiting to 4
// certifies tile t+1 per-wave; the barrier makes it block-wide before anyone computes it.
// Slot overwrite safety: tile t+3 (issued iter t+1) reuses slot t%3, whose ds_reads
// completed before iter t's closing barrier. Occupancy stays 3 blocks/CU (48 KB LDS).
// XCD supertile swizzle kept from r2 (FETCH 36->21 MB).

__global__ __launch_bounds__(256, 3) void gemm_qkv(const u16* __restrict__ A,   // xb [4096][1024]
                                                   const u16* __restrict__ Bt,  // WqkvT [3072][1024]
                                                   const float* __restrict__ bias,
                                                   u16* __restrict__ Qb, u16* __restrict__ Kb,
                                                   u16* __restrict__ Vt) {
  __shared__ u16 lA[3][128 * 32], lB[3][128 * 32];  // 48 KB
  const int tid = threadIdx.x;
  const int wave = tid >> 6, lane = tid & 63, ln = lane & 15, quad = lane >> 4;
  const int lin = blockIdx.y * 24 + blockIdx.x;
  const int reg = lin & 7, idx = lin >> 3;      // 8 regions x 96 tiles
  const int mr = idx / 12, nr = idx - mr * 12;  // region = 8 Mpanels x 12 Npanels
  const int m0 = ((reg >> 1) * 8 + mr) * 128;
  const int n0 = (((reg & 1) * 12) + nr) * 128;
  const int wm = (wave & 1) * 64, wn = (wave >> 1) * 64;
  f32x4 acc[4][4] = {};

  auto issue = [&](u16* dA, u16* dB, int k0) {
#pragma unroll
    for (int i = 0; i < 2; ++i) {
      int rb = wave * 2 + i;  // 0..7
      gload_lds16(A + (size_t)(m0 + rb * 16 + ln) * 1024 + k0 + quad * 8, dA + rb * 512);
      gload_lds16(Bt + (size_t)(n0 + rb * 16 + ln) * 1024 + k0 + quad * 8, dB + rb * 512);
    }
  };
  auto compute = [&](const u16* sA, const u16* sB) {
    bf16x8 a[4], b[4];
#pragma unroll
    for (int i = 0; i < 4; ++i) {
      a[i] = load_frag(sA + (wm / 16 + i) * 512 + quad * 128 + ln * 8);
      b[i] = load_frag(sB + (wn / 16 + i) * 512 + quad * 128 + ln * 8);
    }
#pragma unroll
    for (int mt = 0; mt < 4; ++mt)
#pragma unroll
      for (int nt = 0; nt < 4; ++nt) acc[mt][nt] = mfma16(a[mt], b[nt], acc[mt][nt]);
  };

  // prologue: tiles 0,1 in flight; certify tile 0 (8 outstanding -> 4)
  issue(lA[0], lB[0], 0);
  issue(lA[1], lB[1], 32);
  asm volatile("s_waitcnt vmcnt(4)" ::: "memory");
  asm volatile("s_barrier" ::: "memory");

  // 30 steady iters (t = 0..29), slot pattern repeats every 3
  for (int tt = 0; tt < 10; ++tt) {
    const int t = tt * 3;
    issue(lA[2], lB[2], (t + 2) * 32);
    compute(lA[0], lB[0]);
    asm volatile("s_waitcnt vmcnt(4)" ::: "memory");
    asm volatile("s_barrier" ::: "memory");
    issue(lA[0], lB[0], (t + 3) * 32);
    compute(lA[1], lB[1]);
    asm volatile("s_waitcnt vmcnt(4)" ::: "memory");
    asm volatile("s_barrier" ::: "memory");
    issue(lA[1], lB[1], (t + 4) * 32);
    compute(lA[2], lB[2]);
    asm volatile("s_waitcnt vmcnt(4)" ::: "memory");
    asm volatile("s_barrier" ::: "memory");
  }
  // tail: tiles 30 (slot 0) and 31 (slot 1)
  compute(lA[0], lB[0]);
  asm volatile("s_waitcnt vmcnt(0)" ::: "memory");
  asm volatile("s_barrier" ::: "memory");
  compute(lA[1], lB[1]);

#pragma unroll
  for (int mt = 0; mt < 4; ++mt) {
    int row = m0 + wm + mt * 16 + quad * 4;
    int bb = row >> 11, s0 = row & 2047;
#pragma unroll
    for (int nt = 0; nt < 4; ++nt) {
      int col = n0 + wn + nt * 16 + ln;
      float bv = bias[col];
      int h = col / 192, rem = col - h * 192, t3 = rem >> 6, d = rem & 63;
      int bh = bb * NUM_HEADS + h;
      if (t3 == 2) {  // V -> transposed layout [bh][d][s], 4 consecutive s packed
        uint2 pk;
        pk.x = cvt_pk_bf16(acc[mt][nt][0] + bv, acc[mt][nt][1] + bv);
        pk.y = cvt_pk_bf16(acc[mt][nt][2] + bv, acc[mt][nt][3] + bv);
        *(uint2*)(Vt + ((size_t)bh * 64 + d) * SEQ + s0) = pk;
      } else {
        u16* dst = (t3 == 0) ? Qb : Kb;
#pragma unroll
        for (int r = 0; r < 4; ++r)
          dst[((size_t)bh * SEQ + s0 + r) * 64 + d] = f2bfu(acc[mt][nt][r] + bv);
      }
    }
  }
}

// ---------------- flash attention, balanced-pair blocks + 128-key super-tiles ----------------
// Block j (0..15): q-tiles lo=j, hi=31-j. 8 waves: 0-3 own lo rows, 4-7 own hi rows.
// NEW (r3): DMA latency hidden instead of serialized. K is double-buffered (2 slots);
// per iter s: B1 -> V-waves issue V(s) (hidden under QK^T+softmax, certified by B2's
// implicit vmcnt(0)+barrier) -> QK^T(s)+softmax from lK[s&1] -> B2 -> K-waves issue
// K(s+1) into slot (s+1)&1 (hidden under PV, certified at next B1's implicit vmcnt(0))
// -> PV(s) from lV. Prologue stages K(0); B1(0)'s implicit drain certifies it.
// Math identical to r2. LDS 66 KB -> 2 blocks/CU (= grid residency).
// XCD swizzle: each XCD owns 4 consecutive heads x all 16 j-blocks.

__global__ __launch_bounds__(512) void attn_kernel(const u16* __restrict__ Qb,
                                                   const u16* __restrict__ Kb,
                                                   const u16* __restrict__ Vt,
                                                   u16* __restrict__ Ob) {
  __shared__ u16 lK[2 * 2 * 64 * 64];  // [slot][half][frag-order], 16 KB per slot
  __shared__ u16 lV[2 * 64 * 64];      // [half][frag-order], 16 KB
  __shared__ u16 lP[8][1152];          // per-wave P swizzle (1024 used) + epilogue (16x72)
  const int tid = threadIdx.x;
  const int wave = tid >> 6, lane = tid & 63;
  const int ln = lane & 15, quad = lane >> 4;
  const int lin = blockIdx.y * 16 + blockIdx.x;   // 512 blocks
  const int xreg = lin & 7, xidx = lin >> 3;      // XCD region, 64 blocks each
  const int j = xidx & 15;                        // q-block 0..15 (j=0 heaviest, early)
  const int bh = xreg * 4 + (xidx >> 4);          // 4 consecutive heads per XCD
  const int lo = j, hi = 31 - j;
  const int myt = (wave < 4) ? lo : hi;
  const int q0w = myt * 64 + (wave & 3) * 16;  // this wave's 16-row base
  const int sD = myt >> 1;                     // this wave's diagonal super-tile
  const int nsup = (hi + 2) >> 1;              // block-wide super-iteration count
  const u16* Qg = Qb + (size_t)bh * SEQ * 64;
  const u16* Kg = Kb + (size_t)bh * SEQ * 64;
  const u16* Vg = Vt + (size_t)bh * 64 * SEQ;
  u16* lPw = lP[wave];

  // Q B-frags, loaded once
  bf16x8 qf[2];
#pragma unroll
  for (int ks = 0; ks < 2; ++ks)
    qf[ks] = load_frag(Qg + (size_t)(q0w + ln) * 64 + ks * 32 + quad * 8);

  // staging: waves 0-3 own the 16 K chunks (1 KB each), waves 4-7 the 16 V chunks.
  const u16* sp[4];
  u16* dp[4];
#pragma unroll
  for (int i = 0; i < 4; ++i) {
    if (wave < 4) {
      int c = wave * 4 + i, half = c >> 3, cc = c & 7, rb = cc >> 1, kgh = cc & 1;
      sp[i] = Kg + (size_t)(half * 64 + rb * 16 + ln) * 64 + (kgh * 4 + quad) * 8;
      dp[i] = lK + half * 4096 + rb * 1024 + kgh * 512;
    } else {
      int c2 = wave * 4 - 16 + i, half = c2 >> 3, cc = c2 & 7, rb = cc >> 1, kgh = cc & 1;
      sp[i] = Vg + (size_t)(rb * 16 + ln) * SEQ + half * 64 + (kgh * 4 + quad) * 8;
      dp[i] = lV + half * 4096 + rb * 1024 + kgh * 512;
    }
  }
  // prologue: K(0) -> slot 0 (certified by B1(0)'s implicit vmcnt(0)+barrier)
  if (wave < 4) {
#pragma unroll
    for (int i = 0; i < 4; ++i) gload_lds16(sp[i], dp[i]);
  }

  f32x4 o[4] = {};     // O^T: row d=dt*16+quad*4+r, col q=ln
  float m_r = -1e30f;  // raw-score domain
  float l_r = 0.f;
  const float SC = 0.18033688011112042f;  // log2(e) / sqrt(64)
  const int qq = q0w + ln;

  for (int s = 0; s < nsup; ++s) {
    __syncthreads();  // B1: PV(s-1) done (lV free); K(s) landed (stagers' vmcnt drained)
    if (wave >= 4) {  // issue V(s); lands by B2, hidden under QK^T+softmax
#pragma unroll
      for (int i = 0; i < 4; ++i) gload_lds16(sp[i] + (size_t)s * 128, dp[i]);
    }

    if (s <= sD) {
      // S^T: 128 keys x 16 q, from lK slot s&1
      const u16* lKs = lK + (s & 1) * 8192;
      f32x4 sc[2][4] = {};
#pragma unroll
      for (int h = 0; h < 2; ++h)
#pragma unroll
        for (int mt = 0; mt < 4; ++mt)
#pragma unroll
          for (int ks = 0; ks < 2; ++ks) {
            bf16x8 kf = load_frag(lKs + h * 4096 + mt * 1024 + (ks * 4 + quad) * 128 + ln * 8);
            sc[h][mt] = mfma16(kf, qf[ks], sc[h][mt]);
          }
      // causal mask only on this wave's diagonal super-tile (covers phantom half too)
      if (s == sD) {
#pragma unroll
        for (int h = 0; h < 2; ++h)
#pragma unroll
          for (int mt = 0; mt < 4; ++mt) {
            int key0 = (2 * s + h) * 64 + mt * 16 + quad * 4;
#pragma unroll
            for (int r = 0; r < 4; ++r)
              if (key0 + r > qq) sc[h][mt][r] = -1e30f;
          }
      }
      // merged online softmax over 32 in-lane scores + quad butterfly
      float mloc = sc[0][0][0];
#pragma unroll
      for (int h = 0; h < 2; ++h)
#pragma unroll
        for (int mt = 0; mt < 4; ++mt)
#pragma unroll
          for (int r = 0; r < 4; ++r) mloc = fmaxf(mloc, sc[h][mt][r]);
      mloc = fmaxf(mloc, __shfl_xor(mloc, 16));
      mloc = fmaxf(mloc, __shfl_xor(mloc, 32));
      float mnew = fmaxf(m_r, mloc);
      float alpha = __builtin_amdgcn_exp2f((m_r - mnew) * SC);
      float nmsc = -mnew * SC;
      float sum = 0.f;
#pragma unroll
      for (int h = 0; h < 2; ++h)
#pragma unroll
        for (int mt = 0; mt < 4; ++mt)
#pragma unroll
          for (int r = 0; r < 4; ++r) {
            float p = __builtin_amdgcn_exp2f(__builtin_fmaf(sc[h][mt][r], SC, nmsc));
            sc[h][mt][r] = p;
            sum += p;
          }
      sum += __shfl_xor(sum, 16);
      sum += __shfl_xor(sum, 32);
      l_r = l_r * alpha + sum;
      m_r = mnew;
#pragma unroll
      for (int dt = 0; dt < 4; ++dt) o[dt] *= alpha;

      __syncthreads();  // B2: V(s) (and K(s+1) of prev iter pattern) landed block-wide
      if (wave < 4 && s + 1 < nsup) {  // issue K(s+1); lands by next B1, hidden under PV
        u16* dsl = (u16*)((s + 1) & 1 ? 8192 : 0);
#pragma unroll
        for (int i = 0; i < 4; ++i)
          gload_lds16(sp[i] + (size_t)(s + 1) * (128 * 64), dp[i] + ((s + 1) & 1) * 8192);
        (void)dsl;
      }

      // per half: P -> wave-private swizzled LDS, then O^T += V^T·P^T
#pragma unroll
      for (int h = 0; h < 2; ++h) {
#pragma unroll
        for (int mt = 0; mt < 4; ++mt) {
          uint2 pk;
          pk.x = cvt_pk_bf16(sc[h][mt][0], sc[h][mt][1]);
          pk.y = cvt_pk_bf16(sc[h][mt][2], sc[h][mt][3]);
          int addr = ln * 64 + (((mt * 2 + (quad >> 1)) ^ (ln & 7)) * 8) + (quad & 1) * 4;
          *(uint2*)(lPw + addr) = pk;
        }
        bf16x8 pf[2];
#pragma unroll
        for (int ks = 0; ks < 2; ++ks)
          pf[ks] = load_frag(lPw + ln * 64 + (((ks * 4 + quad) ^ (ln & 7)) * 8));
#pragma unroll
        for (int dt = 0; dt < 4; ++dt)
#pragma unroll
          for (int ks = 0; ks < 2; ++ks) {
            bf16x8 av = load_frag(lV + h * 4096 + dt * 1024 + (ks * 4 + quad) * 128 + ln * 8);
            o[dt] = mfma16(av, pf[ks], o[dt]);
          }
      }
    } else {
      __syncthreads();  // B2 for waves that skip compute this iter
      if (wave < 4 && s + 1 < nsup) {
#pragma unroll
        for (int i = 0; i < 4; ++i)
          gload_lds16(sp[i] + (size_t)(s + 1) * (128 * 64), dp[i] + ((s + 1) & 1) * 8192);
      }
    }
  }

  // epilogue: normalize, transpose O^T -> [q][d] via wave-private LDS, 16B stores
  float inv = 1.f / l_r;
#pragma unroll
  for (int dt = 0; dt < 4; ++dt) {
    uint2 pk;
    pk.x = cvt_pk_bf16(o[dt][0] * inv, o[dt][1] * inv);
    pk.y = cvt_pk_bf16(o[dt][2] * inv, o[dt][3] * inv);
    *(uint2*)(lPw + ln * 72 + dt * 16 + quad * 4) = pk;
  }
  const int b = bh >> 4, h2 = bh & 15;
#pragma unroll
  for (int i = 0; i < 2; ++i) {
    int c = lane + i * 64;
    int qq2 = c >> 3, dg = c & 7;
    uint4 val = *(const uint4*)(lPw + qq2 * 72 + dg * 8);
    *(uint4*)(Ob + ((size_t)b * SEQ + q0w + qq2) * 1024 + h2 * 64 + dg * 8) = val;
  }
}

// ---------------- GEMM 2: out = values @ W_out + b (fp32 out) ----------------
// 128(M) x 64(N) tile, BK=32. Same 3-slot rotation / single-barrier K-loop as gemm_qkv
// (vmcnt(3): issue is 3 loads/wave). 36 KB LDS, 3 blocks/CU. XCD supertile swizzle.

__global__ __launch_bounds__(256, 3) void gemm_out(const u16* __restrict__ A,   // Ob [4096][1024]
                                                   const u16* __restrict__ Bt,  // WoutT [1024][1024]
                                                   const float* __restrict__ bias,
                                                   float* __restrict__ out) {
  __shared__ u16 lA[3][128 * 32], lB[3][64 * 32];  // 36 KB
  const int tid = threadIdx.x;
  const int wave = tid >> 6, lane = tid & 63, ln = lane & 15, quad = lane >> 4;
  const int lin = blockIdx.y * 16 + blockIdx.x;
  const int reg = lin & 7, idx = lin >> 3;  // 8 regions x 64 tiles
  const int mr = idx >> 3, nr = idx & 7;    // region = 8 Mpanels x 8 Npanels
  const int m0 = ((reg >> 1) * 8 + mr) * 128;
  const int n0 = (((reg & 1) * 8) + nr) * 64;
  f32x4 acc[2][4] = {};

  auto issue = [&](u16* dA, u16* dB, int k0) {
#pragma unroll
    for (int i = 0; i < 3; ++i) {
      int c = wave * 3 + i;  // 12 chunks: 8 A + 4 B
      if (c < 8) {
        gload_lds16(A + (size_t)(m0 + c * 16 + ln) * 1024 + k0 + quad * 8, dA + c * 512);
      } else {
        int cc = c - 8;
        gload_lds16(Bt + (size_t)(n0 + cc * 16 + ln) * 1024 + k0 + quad * 8, dB + cc * 512);
      }
    }
  };
  auto compute = [&](const u16* sA, const u16* sB) {
    bf16x8 a[2], b[4];
#pragma unroll
    for (int i = 0; i < 2; ++i)
      a[i] = load_frag(sA + (wave * 2 + i) * 512 + quad * 128 + ln * 8);
#pragma unroll
    for (int i = 0; i < 4; ++i)
      b[i] = load_frag(sB + i * 512 + quad * 128 + ln * 8);
#pragma unroll
    for (int mt = 0; mt < 2; ++mt)
#pragma unroll
      for (int nt = 0; nt < 4; ++nt) acc[mt][nt] = mfma16(a[mt], b[nt], acc[mt][nt]);
  };

  issue(lA[0], lB[0], 0);
  issue(lA[1], lB[1], 32);
  asm volatile("s_waitcnt vmcnt(3)" ::: "memory");
  asm volatile("s_barrier" ::: "memory");

  for (int tt = 0; tt < 10; ++tt) {
    const int t = tt * 3;
    issue(lA[2], lB[2], (t + 2) * 32);
    compute(lA[0], lB[0]);
    asm volatile("s_waitcnt vmcnt(3)" ::: "memory");
    asm volatile("s_barrier" ::: "memory");
    issue(lA[0], lB[0], (t + 3) * 32);
    compute(lA[1], lB[1]);
    asm volatile("s_waitcnt vmcnt(3)" ::: "memory");
    asm volatile("s_barrier" ::: "memory");
    issue(lA[1], lB[1], (t + 4) * 32);
    compute(lA[2], lB[2]);
    asm volatile("s_waitcnt vmcnt(3)" ::: "memory");
    asm volatile("s_barrier" ::: "memory");
  }
  compute(lA[0], lB[0]);
  asm volatile("s_waitcnt vmcnt(0)" ::: "memory");
  asm volatile("s_barrier" ::: "memory");
  compute(lA[1], lB[1]);

#pragma unroll
  for (int mt = 0; mt < 2; ++mt) {
    int row = m0 + wave * 32 + mt * 16 + quad * 4;
#pragma unroll
    for (int nt = 0; nt < 4; ++nt) {
      int col = n0 + nt * 16 + ln;
      float bv = bias[col];
#pragma unroll
      for (int r = 0; r < 4; ++r)
        out[(size_t)(row + r) * 1024 + col] = acc[mt][nt][r] + bv;
    }
  }
}

// ---------------- launcher ----------------

extern "C" void kernel_launch(void* const* d_in, const int* in_sizes, int n_in,
                              void* d_out, int out_size, void* d_ws, size_t ws_size,
                              hipStream_t stream) {
  const float* x = (const float*)d_in[0];
  const float* W_qkv = (const float*)d_in[1];
  const float* b_qkv = (const float*)d_in[2];
  const float* W_out = (const float*)d_in[3];
  const float* b_out = (const float*)d_in[4];
  float* out = (float*)d_out;

  char* ws = (char*)d_ws;
  const size_t SZ_XB = (size_t)ROWS * D_MODEL * 2;            // 8 MiB
  const size_t SZ_WQKVT = (size_t)3 * D_MODEL * D_MODEL * 2;  // 6 MiB
  const size_t SZ_WOUTT = (size_t)D_MODEL * D_MODEL * 2;      // 2 MiB
  const size_t SZ_HEADS = (size_t)BATCH * NUM_HEADS * SEQ * HEAD_DIM * 2;  // 8 MiB
  u16* xb = (u16*)(ws);
  u16* WqkvT = (u16*)(ws + SZ_XB);
  u16* WoutT = (u16*)(ws + SZ_XB + SZ_WQKVT);
  u16* Qb = (u16*)(ws + SZ_XB + SZ_WQKVT + SZ_WOUTT);
  u16* Kb = (u16*)(ws + SZ_XB + SZ_WQKVT + SZ_WOUTT + SZ_HEADS);
  u16* Vt = (u16*)(ws + SZ_XB + SZ_WQKVT + SZ_WOUTT + 2 * SZ_HEADS);
  u16* Ob = (u16*)(ws + SZ_XB + SZ_WQKVT + SZ_WOUTT + 3 * SZ_HEADS);

  prep_kernel<<<dim3(8192), dim3(256), 0, stream>>>(x, xb, W_qkv, WqkvT, W_out, WoutT);
  gemm_qkv<<<dim3(3 * D_MODEL / 128, ROWS / 128), dim3(256), 0, stream>>>(xb, WqkvT, b_qkv,
                                                                          Qb, Kb, Vt);
  attn_kernel<<<dim3(SEQ / 128, BATCH * NUM_HEADS), dim3(512), 0, stream>>>(Qb, Kb, Vt, Ob);
  gemm_out<<<dim3(D_MODEL / 64, ROWS / 128), dim3(256), 0, stream>>>(Ob, WoutT, b_out, out);
}

// Round 5
// 200.749 us; speedup vs baseline: 1.0614x; 1.0072x over previous
//
#include <hip/hip_runtime.h>
#include <hip/hip_bf16.h>

#define D_MODEL 1024
#define NUM_HEADS 16
#define HEAD_DIM 64
#define SEQ 2048
#define BATCH 2
#define ROWS (BATCH * SEQ)  // 4096

typedef unsigned short u16;
typedef __bf16 bf16x8 __attribute__((ext_vector_type(8)));
typedef float f32x4 __attribute__((ext_vector_type(4)));

__device__ inline u16 f2bfu(float f) {
  // RNE float->bf16
  unsigned u = __float_as_uint(f);
  unsigned r = (u + 0x7fffu + ((u >> 16) & 1u)) >> 16;
  return (u16)r;
}

// packed f32x2 -> bf16x2 (one v_cvt_pk_bf16_f32 on gfx950; RNE fallback otherwise)
__device__ inline unsigned cvt_pk_bf16(float a, float b) {
#if __has_builtin(__builtin_amdgcn_cvt_pk_bf16_f32)
  auto r = __builtin_amdgcn_cvt_pk_bf16_f32(a, b);
  unsigned u;
  __builtin_memcpy(&u, &r, 4);
  return u;
#else
  return (unsigned)f2bfu(a) | ((unsigned)f2bfu(b) << 16);
#endif
}

__device__ inline f32x4 mfma16(bf16x8 a, bf16x8 b, f32x4 c) {
  return __builtin_amdgcn_mfma_f32_16x16x32_bf16(a, b, c, 0, 0, 0);
}

__device__ inline bf16x8 load_frag(const u16* p) {
  union { uint4 v; bf16x8 f; } u;
  u.v = *(const uint4*)p;
  return u.f;
}

// async global->LDS, 16B per lane; LDS dest = wave-uniform base + lane*16
__device__ inline void gload_lds16(const u16* g, u16* l) {
  __builtin_amdgcn_global_load_lds((const __attribute__((address_space(1))) void*)g,
                                   (__attribute__((address_space(3))) void*)l, 16, 0, 0);
}

// ---------------- fused prep: cvt x + transpose-cvt both weight matrices ----------------
// grid: [0,4096) cvt_x chunks; [4096,7168) W_qkv 32x32 tiles; [7168,8192) W_out tiles.

__global__ __launch_bounds__(256) void prep_kernel(const float* __restrict__ x,
                                                   u16* __restrict__ xb,
                                                   const float* __restrict__ Wq,
                                                   u16* __restrict__ WqT,
                                                   const float* __restrict__ Wo,
                                                   u16* __restrict__ WoT) {
  __shared__ float t[32][33];
  const int bid = blockIdx.x;
  if (bid < 4096) {
    int i = bid * 256 + threadIdx.x;  // 4 floats each
    float4 v = ((const float4*)x)[i];
    uint2 o;
    o.x = cvt_pk_bf16(v.x, v.y);
    o.y = cvt_pk_bf16(v.z, v.w);
    ((uint2*)xb)[i] = o;
    return;
  }
  const float* W;
  u16* Wt;
  int N, tIdx;
  if (bid < 4096 + 3072) { W = Wq; Wt = WqT; N = 3072; tIdx = bid - 4096; }
  else                   { W = Wo; Wt = WoT; N = 1024; tIdx = bid - 7168; }
  const int k0 = (tIdx & 31) * 32, n0 = (tIdx >> 5) * 32;
  const int c = threadIdx.x & 31, r8 = threadIdx.x >> 5;
#pragma unroll
  for (int i = 0; i < 4; i++) {
    int r = r8 + i * 8;
    t[r][c] = W[(size_t)(k0 + r) * N + n0 + c];
  }
  __syncthreads();
#pragma unroll
  for (int i = 0; i < 4; i++) {
    int r = r8 + i * 8;
    Wt[(size_t)(n0 + r) * 1024 + k0 + c] = f2bfu(t[c][r]);
  }
}

// ---------------- GEMM 1: qkv = x @ W_qkv + b -> Qb/Kb [bh][s][64], Vt [bh][d][s] ----------------
// CONTROL (unchanged from r3): 128x128 tile, BK=32, 3-slot LDS rotation,
// one barrier + counted vmcnt(4) per K-step, XCD supertile swizzle. ~56 us, MfmaUtil ~17%.

__global__ __launch_bounds__(256, 3) void gemm_qkv(const u16* __restrict__ A,   // xb [4096][1024]
                                                   const u16* __restrict__ Bt,  // WqkvT [3072][1024]
                                                   const float* __restrict__ bias,
                                                   u16* __restrict__ Qb, u16* __restrict__ Kb,
                                                   u16* __restrict__ Vt) {
  __shared__ u16 lA[3][128 * 32], lB[3][128 * 32];  // 48 KB
  const int tid = threadIdx.x;
  const int wave = tid >> 6, lane = tid & 63, ln = lane & 15, quad = lane >> 4;
  const int lin = blockIdx.y * 24 + blockIdx.x;
  const int reg = lin & 7, idx = lin >> 3;      // 8 regions x 96 tiles
  const int mr = idx / 12, nr = idx - mr * 12;  // region = 8 Mpanels x 12 Npanels
  const int m0 = ((reg >> 1) * 8 + mr) * 128;
  const int n0 = (((reg & 1) * 12) + nr) * 128;
  const int wm = (wave & 1) * 64, wn = (wave >> 1) * 64;
  f32x4 acc[4][4] = {};

  auto issue = [&](u16* dA, u16* dB, int k0) {
#pragma unroll
    for (int i = 0; i < 2; ++i) {
      int rb = wave * 2 + i;  // 0..7
      gload_lds16(A + (size_t)(m0 + rb * 16 + ln) * 1024 + k0 + quad * 8, dA + rb * 512);
      gload_lds16(Bt + (size_t)(n0 + rb * 16 + ln) * 1024 + k0 + quad * 8, dB + rb * 512);
    }
  };
  auto compute = [&](const u16* sA, const u16* sB) {
    bf16x8 a[4], b[4];
#pragma unroll
    for (int i = 0; i < 4; ++i) {
      a[i] = load_frag(sA + (wm / 16 + i) * 512 + quad * 128 + ln * 8);
      b[i] = load_frag(sB + (wn / 16 + i) * 512 + quad * 128 + ln * 8);
    }
#pragma unroll
    for (int mt = 0; mt < 4; ++mt)
#pragma unroll
      for (int nt = 0; nt < 4; ++nt) acc[mt][nt] = mfma16(a[mt], b[nt], acc[mt][nt]);
  };

  // prologue: tiles 0,1 in flight; certify tile 0 (8 outstanding -> 4)
  issue(lA[0], lB[0], 0);
  issue(lA[1], lB[1], 32);
  asm volatile("s_waitcnt vmcnt(4)" ::: "memory");
  asm volatile("s_barrier" ::: "memory");

  // 30 steady iters (t = 0..29), slot pattern repeats every 3
  for (int tt = 0; tt < 10; ++tt) {
    const int t = tt * 3;
    issue(lA[2], lB[2], (t + 2) * 32);
    compute(lA[0], lB[0]);
    asm volatile("s_waitcnt vmcnt(4)" ::: "memory");
    asm volatile("s_barrier" ::: "memory");
    issue(lA[0], lB[0], (t + 3) * 32);
    compute(lA[1], lB[1]);
    asm volatile("s_waitcnt vmcnt(4)" ::: "memory");
    asm volatile("s_barrier" ::: "memory");
    issue(lA[1], lB[1], (t + 4) * 32);
    compute(lA[2], lB[2]);
    asm volatile("s_waitcnt vmcnt(4)" ::: "memory");
    asm volatile("s_barrier" ::: "memory");
  }
  // tail: tiles 30 (slot 0) and 31 (slot 1)
  compute(lA[0], lB[0]);
  asm volatile("s_waitcnt vmcnt(0)" ::: "memory");
  asm volatile("s_barrier" ::: "memory");
  compute(lA[1], lB[1]);

#pragma unroll
  for (int mt = 0; mt < 4; ++mt) {
    int row = m0 + wm + mt * 16 + quad * 4;
    int bb = row >> 11, s0 = row & 2047;
#pragma unroll
    for (int nt = 0; nt < 4; ++nt) {
      int col = n0 + wn + nt * 16 + ln;
      float bv = bias[col];
      int h = col / 192, rem = col - h * 192, t3 = rem >> 6, d = rem & 63;
      int bh = bb * NUM_HEADS + h;
      if (t3 == 2) {  // V -> transposed layout [bh][d][s], 4 consecutive s packed
        uint2 pk;
        pk.x = cvt_pk_bf16(acc[mt][nt][0] + bv, acc[mt][nt][1] + bv);
        pk.y = cvt_pk_bf16(acc[mt][nt][2] + bv, acc[mt][nt][3] + bv);
        *(uint2*)(Vt + ((size_t)bh * 64 + d) * SEQ + s0) = pk;
      } else {
        u16* dst = (t3 == 0) ? Qb : Kb;
#pragma unroll
        for (int r = 0; r < 4; ++r)
          dst[((size_t)bh * SEQ + s0 + r) * 64 + d] = f2bfu(acc[mt][nt][r] + bv);
      }
    }
  }
}

// ---------------- flash attention, balanced-pair blocks + 128-key super-tiles ----------------
// r3 structure (pipelined K/V DMA, K double-buffered) + r4:
//  - T13 defer-max: skip the O/l rescale when __all(mloc - m_r <= 44) (= exp2-domain
//    THR 8: P bounded by 2^7.9 = 244, safe in bf16; saves 16 muls + exp on most iters)
//  - T5 setprio(1) around QK^T and PV MFMA clusters (attn-verified +4-7%, m191)

__global__ __launch_bounds__(512) void attn_kernel(const u16* __restrict__ Qb,
                                                   const u16* __restrict__ Kb,
                                                   const u16* __restrict__ Vt,
                                                   u16* __restrict__ Ob) {
  __shared__ u16 lK[2 * 2 * 64 * 64];  // [slot][half][frag-order], 16 KB per slot
  __shared__ u16 lV[2 * 64 * 64];      // [half][frag-order], 16 KB
  __shared__ u16 lP[8][1152];          // per-wave P swizzle (1024 used) + epilogue (16x72)
  const int tid = threadIdx.x;
  const int wave = tid >> 6, lane = tid & 63;
  const int ln = lane & 15, quad = lane >> 4;
  const int lin = blockIdx.y * 16 + blockIdx.x;   // 512 blocks
  const int xreg = lin & 7, xidx = lin >> 3;      // XCD region, 64 blocks each
  const int j = xidx & 15;                        // q-block 0..15 (j=0 heaviest, early)
  const int bh = xreg * 4 + (xidx >> 4);          // 4 consecutive heads per XCD
  const int lo = j, hi = 31 - j;
  const int myt = (wave < 4) ? lo : hi;
  const int q0w = myt * 64 + (wave & 3) * 16;  // this wave's 16-row base
  const int sD = myt >> 1;                     // this wave's diagonal super-tile
  const int nsup = (hi + 2) >> 1;              // block-wide super-iteration count
  const u16* Qg = Qb + (size_t)bh * SEQ * 64;
  const u16* Kg = Kb + (size_t)bh * SEQ * 64;
  const u16* Vg = Vt + (size_t)bh * 64 * SEQ;
  u16* lPw = lP[wave];

  // Q B-frags, loaded once
  bf16x8 qf[2];
#pragma unroll
  for (int ks = 0; ks < 2; ++ks)
    qf[ks] = load_frag(Qg + (size_t)(q0w + ln) * 64 + ks * 32 + quad * 8);

  // staging: waves 0-3 own the 16 K chunks (1 KB each), waves 4-7 the 16 V chunks.
  const u16* sp[4];
  u16* dp[4];
#pragma unroll
  for (int i = 0; i < 4; ++i) {
    if (wave < 4) {
      int c = wave * 4 + i, half = c >> 3, cc = c & 7, rb = cc >> 1, kgh = cc & 1;
      sp[i] = Kg + (size_t)(half * 64 + rb * 16 + ln) * 64 + (kgh * 4 + quad) * 8;
      dp[i] = lK + half * 4096 + rb * 1024 + kgh * 512;
    } else {
      int c2 = wave * 4 - 16 + i, half = c2 >> 3, cc = c2 & 7, rb = cc >> 1, kgh = cc & 1;
      sp[i] = Vg + (size_t)(rb * 16 + ln) * SEQ + half * 64 + (kgh * 4 + quad) * 8;
      dp[i] = lV + half * 4096 + rb * 1024 + kgh * 512;
    }
  }
  // prologue: K(0) -> slot 0 (certified by B1(0)'s implicit vmcnt(0)+barrier)
  if (wave < 4) {
#pragma unroll
    for (int i = 0; i < 4; ++i) gload_lds16(sp[i], dp[i]);
  }

  f32x4 o[4] = {};     // O^T: row d=dt*16+quad*4+r, col q=ln
  float m_r = -1e30f;  // raw-score domain
  float l_r = 0.f;
  const float SC = 0.18033688011112042f;  // log2(e) / sqrt(64)
  const int qq = q0w + ln;

  for (int s = 0; s < nsup; ++s) {
    __syncthreads();  // B1: PV(s-1) done (lV free); K(s) landed (stagers' vmcnt drained)
    if (wave >= 4) {  // issue V(s); lands by B2, hidden under QK^T+softmax
#pragma unroll
      for (int i = 0; i < 4; ++i) gload_lds16(sp[i] + (size_t)s * 128, dp[i]);
    }

    if (s <= sD) {
      // S^T: 128 keys x 16 q, from lK slot s&1
      const u16* lKs = lK + (s & 1) * 8192;
      f32x4 sc[2][4] = {};
      __builtin_amdgcn_s_setprio(1);
#pragma unroll
      for (int h = 0; h < 2; ++h)
#pragma unroll
        for (int mt = 0; mt < 4; ++mt)
#pragma unroll
          for (int ks = 0; ks < 2; ++ks) {
            bf16x8 kf = load_frag(lKs + h * 4096 + mt * 1024 + (ks * 4 + quad) * 128 + ln * 8);
            sc[h][mt] = mfma16(kf, qf[ks], sc[h][mt]);
          }
      __builtin_amdgcn_s_setprio(0);
      // causal mask only on this wave's diagonal super-tile (covers phantom half too)
      if (s == sD) {
#pragma unroll
        for (int h = 0; h < 2; ++h)
#pragma unroll
          for (int mt = 0; mt < 4; ++mt) {
            int key0 = (2 * s + h) * 64 + mt * 16 + quad * 4;
#pragma unroll
            for (int r = 0; r < 4; ++r)
              if (key0 + r > qq) sc[h][mt][r] = -1e30f;
          }
      }
      // merged online softmax over 32 in-lane scores + quad butterfly
      float mloc = sc[0][0][0];
#pragma unroll
      for (int h = 0; h < 2; ++h)
#pragma unroll
        for (int mt = 0; mt < 4; ++mt)
#pragma unroll
          for (int r = 0; r < 4; ++r) mloc = fmaxf(mloc, sc[h][mt][r]);
      mloc = fmaxf(mloc, __shfl_xor(mloc, 16));
      mloc = fmaxf(mloc, __shfl_xor(mloc, 32));
      // T13 defer-max: rescale only if some lane's max grew past THR (44 raw = 8 exp2)
      if (!__all(mloc - m_r <= 44.0f)) {
        float mnew = fmaxf(m_r, mloc);
        float alpha = __builtin_amdgcn_exp2f((m_r - mnew) * SC);
        l_r *= alpha;
#pragma unroll
        for (int dt = 0; dt < 4; ++dt) o[dt] *= alpha;
        m_r = mnew;
      }
      float nmsc = -m_r * SC;
      float sum = 0.f;
#pragma unroll
      for (int h = 0; h < 2; ++h)
#pragma unroll
        for (int mt = 0; mt < 4; ++mt)
#pragma unroll
          for (int r = 0; r < 4; ++r) {
            float p = __builtin_amdgcn_exp2f(__builtin_fmaf(sc[h][mt][r], SC, nmsc));
            sc[h][mt][r] = p;
            sum += p;
          }
      sum += __shfl_xor(sum, 16);
      sum += __shfl_xor(sum, 32);
      l_r += sum;

      __syncthreads();  // B2: V(s) landed block-wide
      if (wave < 4 && s + 1 < nsup) {  // issue K(s+1); lands by next B1, hidden under PV
#pragma unroll
        for (int i = 0; i < 4; ++i)
          gload_lds16(sp[i] + (size_t)(s + 1) * (128 * 64), dp[i] + ((s + 1) & 1) * 8192);
      }

      // per half: P -> wave-private swizzled LDS, then O^T += V^T·P^T
#pragma unroll
      for (int h = 0; h < 2; ++h) {
#pragma unroll
        for (int mt = 0; mt < 4; ++mt) {
          uint2 pk;
          pk.x = cvt_pk_bf16(sc[h][mt][0], sc[h][mt][1]);
          pk.y = cvt_pk_bf16(sc[h][mt][2], sc[h][mt][3]);
          int addr = ln * 64 + (((mt * 2 + (quad >> 1)) ^ (ln & 7)) * 8) + (quad & 1) * 4;
          *(uint2*)(lPw + addr) = pk;
        }
        bf16x8 pf[2];
#pragma unroll
        for (int ks = 0; ks < 2; ++ks)
          pf[ks] = load_frag(lPw + ln * 64 + (((ks * 4 + quad) ^ (ln & 7)) * 8));
        __builtin_amdgcn_s_setprio(1);
#pragma unroll
        for (int dt = 0; dt < 4; ++dt)
#pragma unroll
          for (int ks = 0; ks < 2; ++ks) {
            bf16x8 av = load_frag(lV + h * 4096 + dt * 1024 + (ks * 4 + quad) * 128 + ln * 8);
            o[dt] = mfma16(av, pf[ks], o[dt]);
          }
        __builtin_amdgcn_s_setprio(0);
      }
    } else {
      __syncthreads();  // B2 for waves that skip compute this iter
      if (wave < 4 && s + 1 < nsup) {
#pragma unroll
        for (int i = 0; i < 4; ++i)
          gload_lds16(sp[i] + (size_t)(s + 1) * (128 * 64), dp[i] + ((s + 1) & 1) * 8192);
      }
    }
  }

  // epilogue: normalize, transpose O^T -> [q][d] via wave-private LDS, 16B stores
  float inv = 1.f / l_r;
#pragma unroll
  for (int dt = 0; dt < 4; ++dt) {
    uint2 pk;
    pk.x = cvt_pk_bf16(o[dt][0] * inv, o[dt][1] * inv);
    pk.y = cvt_pk_bf16(o[dt][2] * inv, o[dt][3] * inv);
    *(uint2*)(lPw + ln * 72 + dt * 16 + quad * 4) = pk;
  }
  const int b = bh >> 4, h2 = bh & 15;
#pragma unroll
  for (int i = 0; i < 2; ++i) {
    int c = lane + i * 64;
    int qq2 = c >> 3, dg = c & 7;
    uint4 val = *(const uint4*)(lPw + qq2 * 72 + dg * 8);
    *(uint4*)(Ob + ((size_t)b * SEQ + q0w + qq2) * 1024 + h2 * 64 + dg * 8) = val;
  }
}

// ---------------- GEMM 2: out = values @ W_out + b (fp32 out) ----------------
// r4: 128(M) x 64(N) tile, BK=64 (16 MFMA/wave/compute), 3-slot rotation, one barrier
// + counted vmcnt(6) per K-step. Barriers 32 -> 17. LDS 72 KB -> 2 blocks/CU, matching
// the 512-block grid. XCD supertile swizzle kept. launch_bounds (256,2) to match.

__global__ __launch_bounds__(256, 2) void gemm_out(const u16* __restrict__ A,   // Ob [4096][1024]
                                                   const u16* __restrict__ Bt,  // WoutT [1024][1024]
                                                   const float* __restrict__ bias,
                                                   float* __restrict__ out) {
  __shared__ u16 lA[3][128 * 64], lB[3][64 * 64];  // 72 KB
  const int tid = threadIdx.x;
  const int wave = tid >> 6, lane = tid & 63, ln = lane & 15, quad = lane >> 4;
  const int lin = blockIdx.y * 16 + blockIdx.x;
  const int reg = lin & 7, idx = lin >> 3;  // 8 regions x 64 tiles
  const int mr = idx >> 3, nr = idx & 7;    // region = 8 Mpanels x 8 Npanels
  const int m0 = ((reg >> 1) * 8 + mr) * 128;
  const int n0 = (((reg & 1) * 8) + nr) * 64;
  f32x4 acc[2][4] = {};

  // 24 chunks of 1 KB per K-step (16 A + 8 B), 6 per wave. Slot layout: [khalf][rowblk].
  auto issue = [&](u16* dA, u16* dB, int k0) {
#pragma unroll
    for (int i = 0; i < 6; ++i) {
      int c = wave * 6 + i;
      if (c < 16) {
        int kh = c & 1, rb = c >> 1;
        gload_lds16(A + (size_t)(m0 + rb * 16 + ln) * 1024 + k0 + kh * 32 + quad * 8,
                    dA + kh * 4096 + rb * 512);
      } else {
        int c2 = c - 16, kh = c2 & 1, rbn = c2 >> 1;
        gload_lds16(Bt + (size_t)(n0 + rbn * 16 + ln) * 1024 + k0 + kh * 32 + quad * 8,
                    dB + kh * 2048 + rbn * 512);
      }
    }
  };
  auto compute = [&](const u16* sA, const u16* sB) {
    bf16x8 a[2][2], b[4][2];
#pragma unroll
    for (int ks = 0; ks < 2; ++ks) {
#pragma unroll
      for (int i = 0; i < 2; ++i)
        a[i][ks] = load_frag(sA + ks * 4096 + (wave * 2 + i) * 512 + quad * 128 + ln * 8);
#pragma unroll
      for (int i = 0; i < 4; ++i)
        b[i][ks] = load_frag(sB + ks * 2048 + i * 512 + quad * 128 + ln * 8);
    }
#pragma unroll
    for (int ks = 0; ks < 2; ++ks)
#pragma unroll
      for (int mt = 0; mt < 2; ++mt)
#pragma unroll
        for (int nt = 0; nt < 4; ++nt)
          acc[mt][nt] = mfma16(a[mt][ks], b[nt][ks], acc[mt][nt]);
  };

  // prologue: tiles 0,1 in flight (12 loads/wave); certify tile 0
  issue(lA[0], lB[0], 0);
  issue(lA[1], lB[1], 64);
  asm volatile("s_waitcnt vmcnt(6)" ::: "memory");
  asm volatile("s_barrier" ::: "memory");

  // steady: 16 K-steps total; iters t=0..11 via 4x triple-unroll
  for (int tt = 0; tt < 4; ++tt) {
    const int t = tt * 3;
    issue(lA[2], lB[2], (t + 2) * 64);
    compute(lA[0], lB[0]);
    asm volatile("s_waitcnt vmcnt(6)" ::: "memory");
    asm volatile("s_barrier" ::: "memory");
    issue(lA[0], lB[0], (t + 3) * 64);
    compute(lA[1], lB[1]);
    asm volatile("s_waitcnt vmcnt(6)" ::: "memory");
    asm volatile("s_barrier" ::: "memory");
    issue(lA[1], lB[1], (t + 4) * 64);
    compute(lA[2], lB[2]);
    asm volatile("s_waitcnt vmcnt(6)" ::: "memory");
    asm volatile("s_barrier" ::: "memory");
  }
  // t=12: issue tile 14 -> slot 2
  issue(lA[2], lB[2], 14 * 64);
  compute(lA[0], lB[0]);
  asm volatile("s_waitcnt vmcnt(6)" ::: "memory");
  asm volatile("s_barrier" ::: "memory");
  // t=13: issue tile 15 -> slot 0
  issue(lA[0], lB[0], 15 * 64);
  compute(lA[1], lB[1]);
  asm volatile("s_waitcnt vmcnt(6)" ::: "memory");
  asm volatile("s_barrier" ::: "memory");
  // t=14
  compute(lA[2], lB[2]);
  asm volatile("s_waitcnt vmcnt(0)" ::: "memory");
  asm volatile("s_barrier" ::: "memory");
  // t=15
  compute(lA[0], lB[0]);

#pragma unroll
  for (int mt = 0; mt < 2; ++mt) {
    int row = m0 + wave * 32 + mt * 16 + quad * 4;
#pragma unroll
    for (int nt = 0; nt < 4; ++nt) {
      int col = n0 + nt * 16 + ln;
      float bv = bias[col];
#pragma unroll
      for (int r = 0; r < 4; ++r)
        out[(size_t)(row + r) * 1024 + col] = acc[mt][nt][r] + bv;
    }
  }
}

// ---------------- launcher ----------------

extern "C" void kernel_launch(void* const* d_in, const int* in_sizes, int n_in,
                              void* d_out, int out_size, void* d_ws, size_t ws_size,
                              hipStream_t stream) {
  const float* x = (const float*)d_in[0];
  const float* W_qkv = (const float*)d_in[1];
  const float* b_qkv = (const float*)d_in[2];
  const float* W_out = (const float*)d_in[3];
  const float* b_out = (const float*)d_in[4];
  float* out = (float*)d_out;

  char* ws = (char*)d_ws;
  const size_t SZ_XB = (size_t)ROWS * D_MODEL * 2;            // 8 MiB
  const size_t SZ_WQKVT = (size_t)3 * D_MODEL * D_MODEL * 2;  // 6 MiB
  const size_t SZ_WOUTT = (size_t)D_MODEL * D_MODEL * 2;      // 2 MiB
  const size_t SZ_HEADS = (size_t)BATCH * NUM_HEADS * SEQ * HEAD_DIM * 2;  // 8 MiB
  u16* xb = (u16*)(ws);
  u16* WqkvT = (u16*)(ws + SZ_XB);
  u16* WoutT = (u16*)(ws + SZ_XB + SZ_WQKVT);
  u16* Qb = (u16*)(ws + SZ_XB + SZ_WQKVT + SZ_WOUTT);
  u16* Kb = (u16*)(ws + SZ_XB + SZ_WQKVT + SZ_WOUTT + SZ_HEADS);
  u16* Vt = (u16*)(ws + SZ_XB + SZ_WQKVT + SZ_WOUTT + 2 * SZ_HEADS);
  u16* Ob = (u16*)(ws + SZ_XB + SZ_WQKVT + SZ_WOUTT + 3 * SZ_HEADS);

  prep_kernel<<<dim3(8192), dim3(256), 0, stream>>>(x, xb, W_qkv, WqkvT, W_out, WoutT);
  gemm_qkv<<<dim3(3 * D_MODEL / 128, ROWS / 128), dim3(256), 0, stream>>>(xb, WqkvT, b_qkv,
                                                                          Qb, Kb, Vt);
  attn_kernel<<<dim3(SEQ / 128, BATCH * NUM_HEADS), dim3(512), 0, stream>>>(Qb, Kb, Vt, Ob);
  gemm_out<<<dim3(D_MODEL / 64, ROWS / 128), dim3(256), 0, stream>>>(Ob, WoutT, b_out, out);
}